// Round 15
// baseline (805.631 us; speedup 1.0000x reference)
//
#include <hip/hip_runtime.h>

// Decoder_48378511622552 — CSR-sorted, bf16, K=128 MFMA fused GNN decoder (gfx950)
// Round 15: hybrid epilogue — EDGE uses R11-style LDS-roundtrip LN (low reg pressure,
// 16KB LDS, restores 115µs/104MB profile); NODE/DEC12 keep register-direct LN + LIN fusion.

#define HD   128
#define NC   50000
#define NF   150000
#define ECNT 400000
#define OUTD 3
#define SCB  512
#define NB_SCAN ((NF + SCB - 1) / SCB)   // 293

typedef unsigned short u16;
typedef unsigned int   u32;
typedef short bf16x8 __attribute__((ext_vector_type(8)));
typedef float f32x4  __attribute__((ext_vector_type(4)));

__device__ __forceinline__ float bf2f(u32 u){ return __uint_as_float(u << 16); }
__device__ __forceinline__ u32 cvtpk(float a, float b){   // lo = bf16(a), hi = bf16(b)
  u32 r; asm("v_cvt_pk_bf16_f32 %0, %1, %2" : "=v"(r) : "v"(a), "v"(b)); return r;
}
__device__ __forceinline__ u16 f2bf(float f){ return (u16)cvtpk(f, f); }
__device__ __forceinline__ u32 addpk(u32 a, u32 b){
  return cvtpk(bf2f(a & 0xffffu) + bf2f(b & 0xffffu),
               __uint_as_float(a & 0xffff0000u) + __uint_as_float(b & 0xffff0000u));
}
__device__ __forceinline__ float eluf(float x){ return x > 0.f ? x : __expf(x) - 1.f; }
// swizzle for bf16 [32][256B] tiles
__device__ __forceinline__ int SW(int row, int byte){ return row * 256 + (byte ^ ((row & 7) << 4)); }

// ---------------- prep kernels ----------------

__global__ void prep_all_kernel(const float* __restrict__ eW0, const float* __restrict__ eW1,
                                const float* __restrict__ nW0, const float* __restrict__ nW1,
                                const float* __restrict__ uW0, const float* __restrict__ uW1,
                                const float* __restrict__ dW1,
                                u16* c_eW0, u16* c_eW1, u16* c_nW0, u16* c_nW1,
                                u16* c_uW0, u16* c_uW1, u16* c_dW1)
{
  int b = blockIdx.x;
  const float* src; u16* dst; int kb;
  if      (b <  384){ src = eW0; dst = c_eW0; kb = b * 2; }          // K=768 (2 mats)
  else if (b <  512){ src = eW1; dst = c_eW1; kb = (b - 384) * 2; }  // K=256
  else if (b <  768){ src = nW0; dst = c_nW0; kb = (b - 512) * 2; }  // K=512
  else if (b <  896){ src = nW1; dst = c_nW1; kb = (b - 768) * 2; }  // K=256
  else if (b < 1024){ src = uW0; dst = c_uW0; kb = (b - 896) * 2; }  // K=256
  else if (b < 1088){ src = uW1; dst = c_uW1; kb = (b - 1024) * 2; } // K=128
  else              { src = dW1; dst = c_dW1; kb = (b - 1088) * 2; } // K=128
  int t = threadIdx.x;
  int k = kb + (t >> 7), j = t & 127;
  dst[(((k >> 3) * HD + j) << 3) + (k & 7)] = f2bf(src[k * HD + j]);
}

__global__ void f32_to_bf16_vec(const float* __restrict__ in, u16* __restrict__ out, int n8){
  int i = blockIdx.x * blockDim.x + threadIdx.x;
  if (i >= n8) return;
  float4 f0 = ((const float4*)in)[i * 2];
  float4 f1 = ((const float4*)in)[i * 2 + 1];
  ((uint4*)out)[i] = make_uint4(cvtpk(f0.x,f0.y), cvtpk(f0.z,f0.w), cvtpk(f1.x,f1.y), cvtpk(f1.z,f1.w));
}

__global__ void deg_kernel(const int* __restrict__ ei, int* __restrict__ deg){
  int e = blockIdx.x * blockDim.x + threadIdx.x;
  if (e < ECNT) atomicAdd(&deg[ei[ECNT + e]], 1);
}

__global__ void scanA_kernel(const int* __restrict__ deg, int* __restrict__ part){
  __shared__ int s[SCB];
  int t = threadIdx.x, i = blockIdx.x * SCB + t;
  s[t] = (i < NF) ? deg[i] : 0;
  __syncthreads();
  for (int off = SCB/2; off; off >>= 1){ if (t < off) s[t] += s[t + off]; __syncthreads(); }
  if (t == 0) part[blockIdx.x] = s[0];
}

__global__ void scanB_kernel(int* __restrict__ part){
  __shared__ int s[SCB];
  int t = threadIdx.x;
  int v = (t < NB_SCAN) ? part[t] : 0;
  s[t] = v; __syncthreads();
  for (int off = 1; off < SCB; off <<= 1){
    int x = (t >= off) ? s[t - off] : 0;
    __syncthreads(); s[t] += x; __syncthreads();
  }
  if (t < NB_SCAN) part[t] = s[t] - v;   // exclusive
}

__global__ void scanC_kernel(const int* __restrict__ deg, const int* __restrict__ part,
                             int* __restrict__ rowptr){
  __shared__ int s[SCB];
  int t = threadIdx.x, i = blockIdx.x * SCB + t;
  int v = (i < NF) ? deg[i] : 0;
  s[t] = v; __syncthreads();
  for (int off = 1; off < SCB; off <<= 1){
    int x = (t >= off) ? s[t - off] : 0;
    __syncthreads(); s[t] += x; __syncthreads();
  }
  int excl = part[blockIdx.x] + s[t] - v;
  if (i < NF) rowptr[i] = excl;
  if (i == NF - 1) rowptr[NF] = excl + v;
}

__global__ void build_perm_kernel(const int* __restrict__ ei, int* __restrict__ cursor,
                                  int* __restrict__ perm, int* __restrict__ esrc,
                                  int* __restrict__ edst){
  int e = blockIdx.x * blockDim.x + threadIdx.x;
  if (e >= ECNT) return;
  int sI = ei[e], d = ei[ECNT + e];
  int p = atomicAdd(&cursor[d], 1);
  perm[p] = e; esrc[p] = sI; edst[p] = d;
}

// ---------------- standalone LIN2: oA = x@Wa, oB = x@Wb ----------------
__global__ __launch_bounds__(256, 4)
void lin2_kernel(const u16* __restrict__ Wa, const u16* __restrict__ Wb,
                 const u16* __restrict__ x, u16* __restrict__ oA, u16* __restrict__ oB,
                 int n_rows)
{
  __shared__ __align__(16) char ldsA[32 * 256];
  const int tid = threadIdx.x, lane = tid & 63, wid = tid >> 6;
  const int ln = lane & 15, kq = lane >> 4, ncol = wid * 32;

  const int row0 = blockIdx.x << 5;
  #pragma unroll
  for (int c = 0; c < 2; ++c){
    int i = tid + c * 256, row = i >> 4, kk = i & 15, rg = row0 + row;
    if (rg < n_rows)
      *(uint4*)(ldsA + SW(row, kk * 16)) = *(const uint4*)(x + (((size_t)rg) << 7) + (kk << 3));
  }
  __syncthreads();
  bf16x8 af[4][2];
  #pragma unroll
  for (int k0 = 0; k0 < 4; ++k0){
    af[k0][0] = *(const bf16x8*)(ldsA + SW(ln,      k0 * 64 + (kq << 4)));
    af[k0][1] = *(const bf16x8*)(ldsA + SW(16 + ln, k0 * 64 + (kq << 4)));
  }
  const u16* Ws[2] = {Wa, Wb};
  u16*       Os[2] = {oA, oB};
  const f32x4 zz = {0.f, 0.f, 0.f, 0.f};
  #pragma unroll
  for (int w = 0; w < 2; ++w){
    const u16* wp = Ws[w];
    asm volatile("" : "+v"(wp));
    uint4 bfr[4][2];
    #pragma unroll
    for (int k0 = 0; k0 < 4; ++k0)
      #pragma unroll
      for (int nt = 0; nt < 2; ++nt)
        bfr[k0][nt] = *(const uint4*)(wp + (((size_t)((k0*4 + kq)*HD + ncol + nt*16 + ln)) << 3));
    f32x4 cc[2][2] = {{zz, zz}, {zz, zz}};
    #pragma unroll
    for (int k0 = 0; k0 < 4; ++k0){
      bf16x8 w0 = __builtin_bit_cast(bf16x8, bfr[k0][0]);
      bf16x8 w1 = __builtin_bit_cast(bf16x8, bfr[k0][1]);
      cc[0][0] = __builtin_amdgcn_mfma_f32_16x16x32_bf16(af[k0][0], w0, cc[0][0], 0, 0, 0);
      cc[0][1] = __builtin_amdgcn_mfma_f32_16x16x32_bf16(af[k0][0], w1, cc[0][1], 0, 0, 0);
      cc[1][0] = __builtin_amdgcn_mfma_f32_16x16x32_bf16(af[k0][1], w0, cc[1][0], 0, 0, 0);
      cc[1][1] = __builtin_amdgcn_mfma_f32_16x16x32_bf16(af[k0][1], w1, cc[1][1], 0, 0, 0);
    }
    u16* op = Os[w];
    #pragma unroll
    for (int mi = 0; mi < 2; ++mi)
      #pragma unroll
      for (int nt = 0; nt < 2; ++nt)
        #pragma unroll
        for (int r = 0; r < 4; ++r){
          int rg = row0 + mi * 16 + kq * 4 + r;
          if (rg < n_rows) op[(size_t)rg * HD + ncol + nt * 16 + ln] = f2bf(cc[mi][nt][r]);
        }
  }
}

// ---------------- unified fused K=128 MFMA MLP ----------------
enum { M_EDGE = 0, M_NODE = 1, M_DEC12 = 2 };

// EDGE : A=ea; h=elu(A@W0 + P[src]+Q[dst] + b0); cf=h@W1;      out = LN(cf+b1 + A)
//        (PERM=1: gather A rows from f32 eaf via perm, convert inline)
//        epilogue: R11-style LDS roundtrip (low reg pressure)
// NODE : cf1=x@W0 (+ act: CSR-mean(ea)@W1); h=elu(cf1+b0); cf=h@W2; out = LN(cf+b1 + x)
// DEC12: h1=elu(delta@dW0+db0); eac=elu(h1@W0+b0); h=elu(eac@W1 + XU[clus] + b1);
//        cf=h@W2;                                              out = LN(elu(cf+b2) + eac)
// FUSE>0 (NODE/DEC12): after LN store, oF[w] = out_tile @ Wf[w] for blocks row0 < fuse_n.
template<int MODE, int FUSE, int PERM>
__global__ __launch_bounds__(256, 4)
void mlp_kernel(const u16* __restrict__ W0c, const u16* __restrict__ W1c,
                const u16* __restrict__ W2c,
                const float* __restrict__ b0, const float* __restrict__ b1,
                const float* __restrict__ b2,
                const float* __restrict__ gw, const float* __restrict__ bw,
                const u16* __restrict__ tabA, const u16* __restrict__ addP,
                const u16* __restrict__ addQ,
                const int* __restrict__ esrc, const int* __restrict__ edst,
                const int* __restrict__ rowptr, const u16* __restrict__ eatab,
                const int* __restrict__ clus,
                u16* __restrict__ outp, int n_rows,
                const float* __restrict__ dW0, const float* __restrict__ db0,
                const float* __restrict__ pos_c, const float* __restrict__ pos_f,
                const u16* __restrict__ Wf0, const u16* __restrict__ Wf1,
                u16* __restrict__ oF0, u16* __restrict__ oF1, int fuse_n,
                const int* __restrict__ permp, const float* __restrict__ eaf)
{
  constexpr bool ELU2 = (MODE == M_DEC12);
  constexpr bool REGEPI = (MODE != M_EDGE);   // register-direct epilogue

  __shared__ __align__(16) char  ldsA [32 * 256];   // A/x/eac tile (residual source)
  __shared__ __align__(16) char  ldsPQ[32 * 256];   // addend/mean -> h -> r(EDGE)
  __shared__ float ldsSQ[REGEPI ? 32 * 8 : 8];      // per-row wave partials {s,q} x4
  __shared__ float ldsM [REGEPI ? 32 * 2 : 2];      // per-row {mu, rs}

  const int tid  = threadIdx.x;
  const int lane = tid & 63;
  const int wid  = tid >> 6;
  const int ln   = lane & 15, kq = lane >> 4;
  const int ncol = wid * 32;

  bf16x8 b1f[4][2];
  #pragma unroll
  for (int k0 = 0; k0 < 4; ++k0)
    #pragma unroll
    for (int nt = 0; nt < 2; ++nt)
      b1f[k0][nt] = *(const bf16x8*)(W0c + (((size_t)((k0*4 + kq)*HD + ncol + nt*16 + ln)) << 3));

  float b0v[2], b1v[2];
  #pragma unroll
  for (int nt = 0; nt < 2; ++nt){
    int col = ncol + nt*16 + ln;
    b0v[nt] = b0[col]; b1v[nt] = b1[col];
  }
  float bfin[2] = {0.f, 0.f}, gv[2] = {0.f, 0.f}, btv[2] = {0.f, 0.f};
  float gl0 = 0.f, gl1 = 0.f, bt0 = 0.f, bt1 = 0.f;
  if constexpr (REGEPI){
    #pragma unroll
    for (int nt = 0; nt < 2; ++nt){
      int col = ncol + nt*16 + ln;
      bfin[nt] = (MODE == M_DEC12) ? b2[col] : b1v[nt];
      gv[nt] = gw[col]; btv[nt] = bw[col];
    }
  } else {
    gl0 = gw[lane]; gl1 = gw[64 + lane]; bt0 = bw[lane]; bt1 = bw[64 + lane];
  }

  const int row0 = blockIdx.x << 5;
  const f32x4 zz = {0.f, 0.f, 0.f, 0.f};
  f32x4 cf[2][2];

  if constexpr (MODE == M_EDGE){
    // ---- stage: ea -> ldsA (PERM: gather f32 + convert), P+Q -> ldsPQ ----
    #pragma unroll
    for (int c = 0; c < 2; ++c){
      int i = tid + c * 256, row = i >> 4, kk = i & 15, rg = row0 + row;   // ECNT%32==0
      uint4 va;
      if constexpr (PERM){
        int e = permp[rg];
        const float4* src = (const float4*)(eaf + (((size_t)e) << 7) + (kk << 3));
        float4 fa = src[0], fb = src[1];
        va = make_uint4(cvtpk(fa.x,fa.y), cvtpk(fa.z,fa.w), cvtpk(fb.x,fb.y), cvtpk(fb.z,fb.w));
      } else {
        va = *(const uint4*)(tabA + (((size_t)rg) << 7) + (kk << 3));
      }
      *(uint4*)(ldsA + SW(row, kk * 16)) = va;
      int sI = esrc[rg], dI = edst[rg];
      uint4 p = *(const uint4*)(addP + (((size_t)sI) << 7) + (kk << 3));
      uint4 q = *(const uint4*)(addQ + (((size_t)dI) << 7) + (kk << 3));
      *(uint4*)(ldsPQ + SW(row, kk * 16)) =
          make_uint4(addpk(p.x,q.x), addpk(p.y,q.y), addpk(p.z,q.z), addpk(p.w,q.w));
    }
    __syncthreads();   // A
    // GEMM1
    cf[0][0]=zz; cf[0][1]=zz; cf[1][0]=zz; cf[1][1]=zz;
    #pragma unroll
    for (int k0 = 0; k0 < 4; ++k0){
      bf16x8 a0 = *(const bf16x8*)(ldsA + SW(ln,      k0 * 64 + (kq << 4)));
      bf16x8 a1 = *(const bf16x8*)(ldsA + SW(16 + ln, k0 * 64 + (kq << 4)));
      cf[0][0] = __builtin_amdgcn_mfma_f32_16x16x32_bf16(a0, b1f[k0][0], cf[0][0], 0, 0, 0);
      cf[0][1] = __builtin_amdgcn_mfma_f32_16x16x32_bf16(a0, b1f[k0][1], cf[0][1], 0, 0, 0);
      cf[1][0] = __builtin_amdgcn_mfma_f32_16x16x32_bf16(a1, b1f[k0][0], cf[1][0], 0, 0, 0);
      cf[1][1] = __builtin_amdgcn_mfma_f32_16x16x32_bf16(a1, b1f[k0][1], cf[1][1], 0, 0, 0);
    }
    // h = elu(cf + pq + b0) -> ldsPQ in place (same-thread RMW at C positions)
    #pragma unroll
    for (int mi = 0; mi < 2; ++mi)
      #pragma unroll
      for (int nt = 0; nt < 2; ++nt)
        #pragma unroll
        for (int r = 0; r < 4; ++r){
          int row = mi * 16 + kq * 4 + r, col = ncol + nt * 16 + ln;
          u16* pp = (u16*)(ldsPQ + SW(row, col * 2));
          *pp = f2bf(eluf(cf[mi][nt][r] + bf2f(*pp) + b0v[nt]));
        }
    __syncthreads();   // B
    // GEMM2
    {
      const u16* w1p = W1c;
      asm volatile("" : "+v"(w1p));
      uint4 b2r[4][2];
      #pragma unroll
      for (int k0 = 0; k0 < 4; ++k0)
        #pragma unroll
        for (int nt = 0; nt < 2; ++nt)
          b2r[k0][nt] = *(const uint4*)(w1p + (((size_t)((k0*4 + kq)*HD + ncol + nt*16 + ln)) << 3));
      cf[0][0]=zz; cf[0][1]=zz; cf[1][0]=zz; cf[1][1]=zz;
      #pragma unroll
      for (int k0 = 0; k0 < 4; ++k0){
        bf16x8 a0 = *(const bf16x8*)(ldsPQ + SW(ln,      k0 * 64 + (kq << 4)));
        bf16x8 a1 = *(const bf16x8*)(ldsPQ + SW(16 + ln, k0 * 64 + (kq << 4)));
        bf16x8 w0 = __builtin_bit_cast(bf16x8, b2r[k0][0]);
        bf16x8 w1 = __builtin_bit_cast(bf16x8, b2r[k0][1]);
        cf[0][0] = __builtin_amdgcn_mfma_f32_16x16x32_bf16(a0, w0, cf[0][0], 0, 0, 0);
        cf[0][1] = __builtin_amdgcn_mfma_f32_16x16x32_bf16(a0, w1, cf[0][1], 0, 0, 0);
        cf[1][0] = __builtin_amdgcn_mfma_f32_16x16x32_bf16(a1, w0, cf[1][0], 0, 0, 0);
        cf[1][1] = __builtin_amdgcn_mfma_f32_16x16x32_bf16(a1, w1, cf[1][1], 0, 0, 0);
      }
    }
    __syncthreads();   // B2: h reads done
    // r = cf + b1 -> ldsPQ (bf16)
    #pragma unroll
    for (int mi = 0; mi < 2; ++mi)
      #pragma unroll
      for (int nt = 0; nt < 2; ++nt)
        #pragma unroll
        for (int r = 0; r < 4; ++r){
          int row = mi * 16 + kq * 4 + r, col = ncol + nt * 16 + ln;
          *(u16*)(ldsPQ + SW(row, col * 2)) = f2bf(cf[mi][nt][r] + b1v[nt]);
        }
    __syncthreads();   // C
    // R11-style LN: wave-per-row, residual from ldsA, 32-lane butterfly
    #pragma unroll
    for (int rr = 0; rr < 8; ++rr){
      int e = wid * 8 + rr, rg = row0 + e;
      float v0 = bf2f(*(const u16*)(ldsPQ + SW(e, lane * 2)));
      float v1 = bf2f(*(const u16*)(ldsPQ + SW(e, (64 + lane) * 2)));
      v0 += bf2f(*(const u16*)(ldsA + SW(e, lane * 2)));
      v1 += bf2f(*(const u16*)(ldsA + SW(e, (64 + lane) * 2)));
      float s = v0 + v1, q = v0 * v0 + v1 * v1;
      #pragma unroll
      for (int o = 32; o; o >>= 1){ s += __shfl_xor(s, o); q += __shfl_xor(q, o); }
      float mu  = s * (1.f / 128.f);
      float var = q * (1.f / 128.f) - mu * mu;
      float rs  = rsqrtf(var + 1e-5f);
      float y0 = (v0 - mu) * rs * gl0 + bt0;
      float y1 = (v1 - mu) * rs * gl1 + bt1;
      outp[(((size_t)rg) << 7) + lane]      = f2bf(y0);
      outp[(((size_t)rg) << 7) + 64 + lane] = f2bf(y1);
    }
    return;
  } else if constexpr (MODE == M_NODE){
    // ---- stage: x -> ldsA ; act: CSR mean -> ldsPQ ----
    #pragma unroll
    for (int c = 0; c < 2; ++c){
      int i = tid + c * 256, row = i >> 4, kk = i & 15, rg = row0 + row;
      if (rg < n_rows)
        *(uint4*)(ldsA + SW(row, kk * 16)) =
            *(const uint4*)(tabA + (((size_t)rg) << 7) + (kk << 3));
    }
    const bool act = (row0 < NC);   // rows >= NC have degree 0 (block-uniform)
    if (act){
      for (int s = 0; s < 8; ++s){
        int nd = wid * 8 + s, rg = row0 + nd;
        if (rg < n_rows){
          int rp0 = rowptr[rg], rp1 = rowptr[rg + 1];
          float s0 = 0.f, s1 = 0.f, t0 = 0.f, t1 = 0.f;
          int i2 = rp0;
          for (; i2 + 3 < rp1; i2 += 4){
            u32 ua = *(const u32*)(eatab + (((size_t) i2     ) << 7) + (lane << 1));
            u32 ub = *(const u32*)(eatab + (((size_t)(i2 + 1)) << 7) + (lane << 1));
            u32 uc = *(const u32*)(eatab + (((size_t)(i2 + 2)) << 7) + (lane << 1));
            u32 ud = *(const u32*)(eatab + (((size_t)(i2 + 3)) << 7) + (lane << 1));
            s0 += bf2f(ua & 0xffffu) + bf2f(ub & 0xffffu);
            s1 += bf2f(ua >> 16)     + bf2f(ub >> 16);
            t0 += bf2f(uc & 0xffffu) + bf2f(ud & 0xffffu);
            t1 += bf2f(uc >> 16)     + bf2f(ud >> 16);
          }
          for (; i2 < rp1; ++i2){
            u32 ua = *(const u32*)(eatab + (((size_t)i2) << 7) + (lane << 1));
            s0 += bf2f(ua & 0xffffu); s1 += bf2f(ua >> 16);
          }
          s0 += t0; s1 += t1;
          int dg = rp1 - rp0;
          float rd = 1.f / (float)(dg > 0 ? dg : 1);
          *(u32*)(ldsPQ + SW(nd, lane << 2)) = cvtpk(s0 * rd, s1 * rd);
        }
      }
    }
    __syncthreads();   // A
    // GEMM1: cf = x @ nW0a
    cf[0][0]=zz; cf[0][1]=zz; cf[1][0]=zz; cf[1][1]=zz;
    #pragma unroll
    for (int k0 = 0; k0 < 4; ++k0){
      bf16x8 a0 = *(const bf16x8*)(ldsA + SW(ln,      k0 * 64 + (kq << 4)));
      bf16x8 a1 = *(const bf16x8*)(ldsA + SW(16 + ln, k0 * 64 + (kq << 4)));
      cf[0][0] = __builtin_amdgcn_mfma_f32_16x16x32_bf16(a0, b1f[k0][0], cf[0][0], 0, 0, 0);
      cf[0][1] = __builtin_amdgcn_mfma_f32_16x16x32_bf16(a0, b1f[k0][1], cf[0][1], 0, 0, 0);
      cf[1][0] = __builtin_amdgcn_mfma_f32_16x16x32_bf16(a1, b1f[k0][0], cf[1][0], 0, 0, 0);
      cf[1][1] = __builtin_amdgcn_mfma_f32_16x16x32_bf16(a1, b1f[k0][1], cf[1][1], 0, 0, 0);
    }
    if (act){
      // cf += mean @ nW0b
      const u16* wbp = W1c;
      asm volatile("" : "+v"(wbp));
      uint4 bbr[4][2];
      #pragma unroll
      for (int k0 = 0; k0 < 4; ++k0)
        #pragma unroll
        for (int nt = 0; nt < 2; ++nt)
          bbr[k0][nt] = *(const uint4*)(wbp + (((size_t)((k0*4 + kq)*HD + ncol + nt*16 + ln)) << 3));
      #pragma unroll
      for (int k0 = 0; k0 < 4; ++k0){
        bf16x8 a0 = *(const bf16x8*)(ldsPQ + SW(ln,      k0 * 64 + (kq << 4)));
        bf16x8 a1 = *(const bf16x8*)(ldsPQ + SW(16 + ln, k0 * 64 + (kq << 4)));
        bf16x8 w0 = __builtin_bit_cast(bf16x8, bbr[k0][0]);
        bf16x8 w1 = __builtin_bit_cast(bf16x8, bbr[k0][1]);
        cf[0][0] = __builtin_amdgcn_mfma_f32_16x16x32_bf16(a0, w0, cf[0][0], 0, 0, 0);
        cf[0][1] = __builtin_amdgcn_mfma_f32_16x16x32_bf16(a0, w1, cf[0][1], 0, 0, 0);
        cf[1][0] = __builtin_amdgcn_mfma_f32_16x16x32_bf16(a1, w0, cf[1][0], 0, 0, 0);
        cf[1][1] = __builtin_amdgcn_mfma_f32_16x16x32_bf16(a1, w1, cf[1][1], 0, 0, 0);
      }
    }
    __syncthreads();   // B: mean reads done
    // h = elu(cf + b0) -> ldsPQ (C positions)
    #pragma unroll
    for (int mi = 0; mi < 2; ++mi)
      #pragma unroll
      for (int nt = 0; nt < 2; ++nt)
        #pragma unroll
        for (int r = 0; r < 4; ++r){
          int row = mi * 16 + kq * 4 + r, col = ncol + nt * 16 + ln;
          *(u16*)(ldsPQ + SW(row, col * 2)) = f2bf(eluf(cf[mi][nt][r] + b0v[nt]));
        }
    __syncthreads();   // C
    // GEMM2: cf = h @ nW1
    {
      const u16* w2p = W2c;
      asm volatile("" : "+v"(w2p));
      uint4 b3r[4][2];
      #pragma unroll
      for (int k0 = 0; k0 < 4; ++k0)
        #pragma unroll
        for (int nt = 0; nt < 2; ++nt)
          b3r[k0][nt] = *(const uint4*)(w2p + (((size_t)((k0*4 + kq)*HD + ncol + nt*16 + ln)) << 3));
      cf[0][0]=zz; cf[0][1]=zz; cf[1][0]=zz; cf[1][1]=zz;
      #pragma unroll
      for (int k0 = 0; k0 < 4; ++k0){
        bf16x8 a0 = *(const bf16x8*)(ldsPQ + SW(ln,      k0 * 64 + (kq << 4)));
        bf16x8 a1 = *(const bf16x8*)(ldsPQ + SW(16 + ln, k0 * 64 + (kq << 4)));
        bf16x8 w0 = __builtin_bit_cast(bf16x8, b3r[k0][0]);
        bf16x8 w1 = __builtin_bit_cast(bf16x8, b3r[k0][1]);
        cf[0][0] = __builtin_amdgcn_mfma_f32_16x16x32_bf16(a0, w0, cf[0][0], 0, 0, 0);
        cf[0][1] = __builtin_amdgcn_mfma_f32_16x16x32_bf16(a0, w1, cf[0][1], 0, 0, 0);
        cf[1][0] = __builtin_amdgcn_mfma_f32_16x16x32_bf16(a1, w0, cf[1][0], 0, 0, 0);
        cf[1][1] = __builtin_amdgcn_mfma_f32_16x16x32_bf16(a1, w1, cf[1][1], 0, 0, 0);
      }
    }
  } else { // M_DEC12
    // ---- stage: h1 = elu(delta@dW0+db0) -> ldsA ; XU[clus] -> ldsPQ ----
    #pragma unroll
    for (int c = 0; c < 2; ++c){
      int i = tid + c * 256, row = i >> 4, c8 = i & 15, rg = row0 + row;
      if (rg < n_rows){
        int cl = clus[rg];
        *(uint4*)(ldsPQ + SW(row, c8 * 16)) =
            *(const uint4*)(addP + (((size_t)cl) << 7) + (c8 << 3));
        float d0 = pos_c[cl * 2]     - pos_f[rg * 2];
        float d1 = pos_c[cl * 2 + 1] - pos_f[rg * 2 + 1];
        u32 wq[4];
        #pragma unroll
        for (int q = 0; q < 4; ++q){
          int cc = c8 * 8 + q * 2;
          float va = eluf(fmaf(d0, dW0[cc],     fmaf(d1, dW0[HD + cc],     db0[cc])));
          float vb = eluf(fmaf(d0, dW0[cc + 1], fmaf(d1, dW0[HD + cc + 1], db0[cc + 1])));
          wq[q] = cvtpk(va, vb);
        }
        *(uint4*)(ldsA + SW(row, c8 * 16)) = make_uint4(wq[0], wq[1], wq[2], wq[3]);
      }
    }
    __syncthreads();   // A
    // GEMM1: cf = h1 @ dW1
    cf[0][0]=zz; cf[0][1]=zz; cf[1][0]=zz; cf[1][1]=zz;
    #pragma unroll
    for (int k0 = 0; k0 < 4; ++k0){
      bf16x8 a0 = *(const bf16x8*)(ldsA + SW(ln,      k0 * 64 + (kq << 4)));
      bf16x8 a1 = *(const bf16x8*)(ldsA + SW(16 + ln, k0 * 64 + (kq << 4)));
      cf[0][0] = __builtin_amdgcn_mfma_f32_16x16x32_bf16(a0, b1f[k0][0], cf[0][0], 0, 0, 0);
      cf[0][1] = __builtin_amdgcn_mfma_f32_16x16x32_bf16(a0, b1f[k0][1], cf[0][1], 0, 0, 0);
      cf[1][0] = __builtin_amdgcn_mfma_f32_16x16x32_bf16(a1, b1f[k0][0], cf[1][0], 0, 0, 0);
      cf[1][1] = __builtin_amdgcn_mfma_f32_16x16x32_bf16(a1, b1f[k0][1], cf[1][1], 0, 0, 0);
    }
    __syncthreads();   // B: h1 reads done
    // eac = elu(cf + b0) -> ldsA (C positions)
    #pragma unroll
    for (int mi = 0; mi < 2; ++mi)
      #pragma unroll
      for (int nt = 0; nt < 2; ++nt)
        #pragma unroll
        for (int r = 0; r < 4; ++r){
          int row = mi * 16 + kq * 4 + r, col = ncol + nt * 16 + ln;
          *(u16*)(ldsA + SW(row, col * 2)) = f2bf(eluf(cf[mi][nt][r] + b0v[nt]));
        }
    __syncthreads();   // C: eac visible
    // GEMM2: cf = eac @ uW0a ; h = elu(cf + XU + b1) -> ldsPQ in place
    {
      const u16* w1p = W1c;
      asm volatile("" : "+v"(w1p));
      uint4 b2r[4][2];
      #pragma unroll
      for (int k0 = 0; k0 < 4; ++k0)
        #pragma unroll
        for (int nt = 0; nt < 2; ++nt)
          b2r[k0][nt] = *(const uint4*)(w1p + (((size_t)((k0*4 + kq)*HD + ncol + nt*16 + ln)) << 3));
      cf[0][0]=zz; cf[0][1]=zz; cf[1][0]=zz; cf[1][1]=zz;
      #pragma unroll
      for (int k0 = 0; k0 < 4; ++k0){
        bf16x8 a0 = *(const bf16x8*)(ldsA + SW(ln,      k0 * 64 + (kq << 4)));
        bf16x8 a1 = *(const bf16x8*)(ldsA + SW(16 + ln, k0 * 64 + (kq << 4)));
        bf16x8 w0 = __builtin_bit_cast(bf16x8, b2r[k0][0]);
        bf16x8 w1 = __builtin_bit_cast(bf16x8, b2r[k0][1]);
        cf[0][0] = __builtin_amdgcn_mfma_f32_16x16x32_bf16(a0, w0, cf[0][0], 0, 0, 0);
        cf[0][1] = __builtin_amdgcn_mfma_f32_16x16x32_bf16(a0, w1, cf[0][1], 0, 0, 0);
        cf[1][0] = __builtin_amdgcn_mfma_f32_16x16x32_bf16(a1, w0, cf[1][0], 0, 0, 0);
        cf[1][1] = __builtin_amdgcn_mfma_f32_16x16x32_bf16(a1, w1, cf[1][1], 0, 0, 0);
      }
      #pragma unroll
      for (int mi = 0; mi < 2; ++mi)
        #pragma unroll
        for (int nt = 0; nt < 2; ++nt)
          #pragma unroll
          for (int r = 0; r < 4; ++r){
            int row = mi * 16 + kq * 4 + r, col = ncol + nt * 16 + ln;
            u16* pp = (u16*)(ldsPQ + SW(row, col * 2));
            *pp = f2bf(eluf(cf[mi][nt][r] + bf2f(*pp) + b1v[nt]));
          }
    }
    __syncthreads();   // D
    // GEMM3: cf = h @ uW1
    {
      const u16* w2p = W2c;
      asm volatile("" : "+v"(w2p));
      uint4 b3r[4][2];
      #pragma unroll
      for (int k0 = 0; k0 < 4; ++k0)
        #pragma unroll
        for (int nt = 0; nt < 2; ++nt)
          b3r[k0][nt] = *(const uint4*)(w2p + (((size_t)((k0*4 + kq)*HD + ncol + nt*16 + ln)) << 3));
      cf[0][0]=zz; cf[0][1]=zz; cf[1][0]=zz; cf[1][1]=zz;
      #pragma unroll
      for (int k0 = 0; k0 < 4; ++k0){
        bf16x8 a0 = *(const bf16x8*)(ldsPQ + SW(ln,      k0 * 64 + (kq << 4)));
        bf16x8 a1 = *(const bf16x8*)(ldsPQ + SW(16 + ln, k0 * 64 + (kq << 4)));
        bf16x8 w0 = __builtin_bit_cast(bf16x8, b3r[k0][0]);
        bf16x8 w1 = __builtin_bit_cast(bf16x8, b3r[k0][1]);
        cf[0][0] = __builtin_amdgcn_mfma_f32_16x16x32_bf16(a0, w0, cf[0][0], 0, 0, 0);
        cf[0][1] = __builtin_amdgcn_mfma_f32_16x16x32_bf16(a0, w1, cf[0][1], 0, 0, 0);
        cf[1][0] = __builtin_amdgcn_mfma_f32_16x16x32_bf16(a1, w0, cf[1][0], 0, 0, 0);
        cf[1][1] = __builtin_amdgcn_mfma_f32_16x16x32_bf16(a1, w1, cf[1][1], 0, 0, 0);
      }
    }
  }

  // ============ register-direct LN epilogue (NODE / DEC12 only) ============
  if constexpr (REGEPI){
    #pragma unroll
    for (int mi = 0; mi < 2; ++mi)
      #pragma unroll
      for (int nt = 0; nt < 2; ++nt)
        #pragma unroll
        for (int r = 0; r < 4; ++r){
          int row = mi * 16 + kq * 4 + r, col = ncol + nt * 16 + ln;
          float v = cf[mi][nt][r] + bfin[nt];
          if constexpr (ELU2) v = eluf(v);
          v += bf2f(*(const u16*)(ldsA + SW(row, col * 2)));
          cf[mi][nt][r] = v;
        }
    float sp[8], qp[8];
    #pragma unroll
    for (int mi = 0; mi < 2; ++mi)
      #pragma unroll
      for (int r = 0; r < 4; ++r){
        int ri = mi * 4 + r;
        float a = cf[mi][0][r], b = cf[mi][1][r];
        sp[ri] = a + b; qp[ri] = a * a + b * b;
      }
    #pragma unroll
    for (int off = 1; off < 16; off <<= 1)
      #pragma unroll
      for (int ri = 0; ri < 8; ++ri){
        sp[ri] += __shfl_xor(sp[ri], off);
        qp[ri] += __shfl_xor(qp[ri], off);
      }
    if (ln == 0){
      #pragma unroll
      for (int mi = 0; mi < 2; ++mi)
        #pragma unroll
        for (int r = 0; r < 4; ++r){
          int row = mi * 16 + kq * 4 + r;
          ldsSQ[row * 8 + wid * 2]     = sp[mi * 4 + r];
          ldsSQ[row * 8 + wid * 2 + 1] = qp[mi * 4 + r];
        }
    }
    __syncthreads();
    if (tid < 32){
      float s = ldsSQ[tid*8+0] + ldsSQ[tid*8+2] + ldsSQ[tid*8+4] + ldsSQ[tid*8+6];
      float q = ldsSQ[tid*8+1] + ldsSQ[tid*8+3] + ldsSQ[tid*8+5] + ldsSQ[tid*8+7];
      float mu  = s * (1.f / 128.f);
      float var = q * (1.f / 128.f) - mu * mu;
      ldsM[tid * 2]     = mu;
      ldsM[tid * 2 + 1] = rsqrtf(var + 1e-5f);
    }
    __syncthreads();
    #pragma unroll
    for (int mi = 0; mi < 2; ++mi)
      #pragma unroll
      for (int r = 0; r < 4; ++r){
        int row = mi * 16 + kq * 4 + r, rg = row0 + row;
        float mu = ldsM[row * 2], rs = ldsM[row * 2 + 1];
        #pragma unroll
        for (int nt = 0; nt < 2; ++nt){
          int col = ncol + nt * 16 + ln;
          float y = (cf[mi][nt][r] - mu) * rs * gv[nt] + btv[nt];
          u16 yb = f2bf(y);
          if (rg < n_rows)
            outp[(((size_t)rg) << 7) + col] = yb;
          if constexpr (FUSE > 0)
            *(u16*)(ldsA + SW(row, col * 2)) = yb;
        }
      }

    // ============ fused next-LIN GEMMs ============
    if constexpr (FUSE > 0){
      __syncthreads();
      if (row0 < fuse_n){   // block-uniform
        bf16x8 af[4][2];
        #pragma unroll
        for (int k0 = 0; k0 < 4; ++k0){
          af[k0][0] = *(const bf16x8*)(ldsA + SW(ln,      k0 * 64 + (kq << 4)));
          af[k0][1] = *(const bf16x8*)(ldsA + SW(16 + ln, k0 * 64 + (kq << 4)));
        }
        const u16* Ws[2] = {Wf0, Wf1};
        u16*       Os[2] = {oF0, oF1};
        #pragma unroll
        for (int w = 0; w < FUSE; ++w){
          const u16* wp = Ws[w];
          asm volatile("" : "+v"(wp));
          uint4 bfr[4][2];
          #pragma unroll
          for (int k0 = 0; k0 < 4; ++k0)
            #pragma unroll
            for (int nt = 0; nt < 2; ++nt)
              bfr[k0][nt] = *(const uint4*)(wp + (((size_t)((k0*4 + kq)*HD + ncol + nt*16 + ln)) << 3));
          f32x4 cc[2][2] = {{zz, zz}, {zz, zz}};
          #pragma unroll
          for (int k0 = 0; k0 < 4; ++k0){
            bf16x8 w0 = __builtin_bit_cast(bf16x8, bfr[k0][0]);
            bf16x8 w1 = __builtin_bit_cast(bf16x8, bfr[k0][1]);
            cc[0][0] = __builtin_amdgcn_mfma_f32_16x16x32_bf16(af[k0][0], w0, cc[0][0], 0, 0, 0);
            cc[0][1] = __builtin_amdgcn_mfma_f32_16x16x32_bf16(af[k0][0], w1, cc[0][1], 0, 0, 0);
            cc[1][0] = __builtin_amdgcn_mfma_f32_16x16x32_bf16(af[k0][1], w0, cc[1][0], 0, 0, 0);
            cc[1][1] = __builtin_amdgcn_mfma_f32_16x16x32_bf16(af[k0][1], w1, cc[1][1], 0, 0, 0);
          }
          u16* op = Os[w];
          #pragma unroll
          for (int mi = 0; mi < 2; ++mi)
            #pragma unroll
            for (int nt = 0; nt < 2; ++nt)
              #pragma unroll
              for (int r = 0; r < 4; ++r){
                int rg = row0 + mi * 16 + kq * 4 + r;
                if (rg < fuse_n)
                  op[(size_t)rg * HD + ncol + nt * 16 + ln] = f2bf(cc[mi][nt][r]);
              }
        }
      }
    }
  }
}

// out0 = elu(x @ oW + ob)
__global__ void outhead_kernel(const u16* __restrict__ x, const float* __restrict__ oW,
                               const float* __restrict__ ob, float* __restrict__ out){
  int row  = (blockIdx.x * blockDim.x + threadIdx.x) >> 6;
  int lane = threadIdx.x & 63;
  if (row >= NF) return;
  float x0 = bf2f(x[((size_t)row << 7) + lane]);
  float x1 = bf2f(x[((size_t)row << 7) + 64 + lane]);
  float s0 = x0 * oW[lane * 3 + 0] + x1 * oW[(64 + lane) * 3 + 0];
  float s1 = x0 * oW[lane * 3 + 1] + x1 * oW[(64 + lane) * 3 + 1];
  float s2 = x0 * oW[lane * 3 + 2] + x1 * oW[(64 + lane) * 3 + 2];
  #pragma unroll
  for (int o = 32; o; o >>= 1){
    s0 += __shfl_xor(s0, o); s1 += __shfl_xor(s1, o); s2 += __shfl_xor(s2, o);
  }
  if (lane == 0){
    out[row * 3 + 0] = eluf(s0 + ob[0]);
    out[row * 3 + 1] = eluf(s1 + ob[1]);
    out[row * 3 + 2] = eluf(s2 + ob[2]);
  }
}

__global__ void idxcopy_kernel(const int* __restrict__ ei, float* __restrict__ out){
  int i = blockIdx.x * blockDim.x + threadIdx.x;
  if (i < 2 * ECNT) out[i] = (float)ei[i];
}

extern "C" void kernel_launch(void* const* d_in, const int* in_sizes, int n_in,
                              void* d_out, int out_size, void* d_ws, size_t ws_size,
                              hipStream_t stream)
{
  const float* x_in  = (const float*)d_in[0];
  const float* ea_in = (const float*)d_in[1];
  const float* pos_c = (const float*)d_in[2];
  const float* pos_f = (const float*)d_in[3];
  const int*   ei    = (const int*)d_in[4];
  const int*   clus  = (const int*)d_in[5];
  const float* eW0 = (const float*)d_in[7];
  const float* eb0 = (const float*)d_in[8];
  const float* eW1 = (const float*)d_in[9];
  const float* eb1 = (const float*)d_in[10];
  const float* eg  = (const float*)d_in[11];
  const float* ebt = (const float*)d_in[12];
  const float* nW0 = (const float*)d_in[13];
  const float* nb0 = (const float*)d_in[14];
  const float* nW1 = (const float*)d_in[15];
  const float* nb1 = (const float*)d_in[16];
  const float* ng  = (const float*)d_in[17];
  const float* nbt = (const float*)d_in[18];
  const float* dW0 = (const float*)d_in[19];
  const float* db0 = (const float*)d_in[20];
  const float* dW1 = (const float*)d_in[21];
  const float* db1 = (const float*)d_in[22];
  const float* uW0 = (const float*)d_in[23];
  const float* ub0 = (const float*)d_in[24];
  const float* uW1 = (const float*)d_in[25];
  const float* ub1 = (const float*)d_in[26];
  const float* ug  = (const float*)d_in[27];
  const float* ubt = (const float*)d_in[28];
  const float* oW  = (const float*)d_in[29];
  const float* ob  = (const float*)d_in[30];

  char* w = (char*)d_ws;
  auto alloc = [&](size_t bytes) -> char* {
    char* p = w; w += (bytes + 255) & ~(size_t)255; return p;
  };
  u16*   ea_s   = (u16*)alloc((size_t)ECNT * HD * 2);
  u16*   xa     = (u16*)alloc((size_t)NC * HD * 2);
  u16*   xb     = (u16*)alloc((size_t)NF * HD * 2);
  u16*   P      = (u16*)alloc((size_t)NC * HD * 2);
  u16*   Q      = (u16*)alloc((size_t)NC * HD * 2);
  u16*   XU     = (u16*)alloc((size_t)NC * HD * 2);
  int*   deg    = (int*)alloc((size_t)NF * 4);
  int*   rowptr = (int*)alloc((size_t)(NF + 1) * 4);
  int*   cursor = (int*)alloc((size_t)NF * 4);
  int*   perm   = (int*)alloc((size_t)ECNT * 4);
  int*   esrc   = (int*)alloc((size_t)ECNT * 4);
  int*   edst   = (int*)alloc((size_t)ECNT * 4);
  int*   part   = (int*)alloc((size_t)SCB * 4);
  u16*   c_eW0  = (u16*)alloc((size_t)2 * 384 * HD * 2);
  u16*   c_eW1  = (u16*)alloc((size_t)2 * HD * HD * 2);
  u16*   c_nW0  = (u16*)alloc((size_t)2 * 256 * HD * 2);
  u16*   c_nW1  = (u16*)alloc((size_t)2 * HD * HD * 2);
  u16*   c_uW0  = (u16*)alloc((size_t)256 * HD * 2);
  u16*   c_uW1  = (u16*)alloc((size_t)HD * HD * 2);
  u16*   c_dW1  = (u16*)alloc((size_t)HD * HD * 2);

  prep_all_kernel<<<1152, 256, 0, stream>>>(eW0, eW1, nW0, nW1, uW0, uW1, dW1,
                                            c_eW0, c_eW1, c_nW0, c_nW1, c_uW0, c_uW1, c_dW1);
  f32_to_bf16_vec<<<(NC * HD / 8 + 255) / 256, 256, 0, stream>>>(x_in, xa, NC * HD / 8);

  hipMemsetAsync(deg, 0, (size_t)NF * 4, stream);
  deg_kernel<<<(ECNT + 255) / 256, 256, 0, stream>>>(ei, deg);
  scanA_kernel<<<NB_SCAN, SCB, 0, stream>>>(deg, part);
  scanB_kernel<<<1, SCB, 0, stream>>>(part);
  scanC_kernel<<<NB_SCAN, SCB, 0, stream>>>(deg, part, rowptr);
  hipMemcpyAsync(cursor, rowptr, (size_t)NF * 4, hipMemcpyDeviceToDevice, stream);
  build_perm_kernel<<<(ECNT + 255) / 256, 256, 0, stream>>>(ei, cursor, perm, esrc, edst);

  auto grd = [](int rows){ return (rows + 31) / 32; };
  const int KS = 16 * HD * 8;   // u16 offset of one 128-K slice in chunked layout

  auto eslice = [&](int i, int s){ return c_eW0 + (size_t)i * 384 * HD + (size_t)s * KS; };

  // EDGE dispatch; PERM=1 for the first (gathers original f32 ea via perm)
  auto edgeP = [&](int i){
    mlp_kernel<M_EDGE, 0, 1><<<grd(ECNT), 256, 0, stream>>>(
      eslice(i, 2), c_eW1 + (size_t)i*HD*HD, nullptr,
      eb0 + i*HD, eb1 + i*HD, nullptr, eg + i*HD, ebt + i*HD,
      ea_s, P, Q, esrc, edst, nullptr, nullptr, nullptr,
      ea_s, ECNT, nullptr, nullptr, nullptr, nullptr,
      nullptr, nullptr, nullptr, nullptr, 0, perm, ea_in);
  };
  auto edge = [&](int i){
    mlp_kernel<M_EDGE, 0, 0><<<grd(ECNT), 256, 0, stream>>>(
      eslice(i, 2), c_eW1 + (size_t)i*HD*HD, nullptr,
      eb0 + i*HD, eb1 + i*HD, nullptr, eg + i*HD, ebt + i*HD,
      ea_s, P, Q, esrc, edst, nullptr, nullptr, nullptr,
      ea_s, ECNT, nullptr, nullptr, nullptr, nullptr,
      nullptr, nullptr, nullptr, nullptr, 0, nullptr, nullptr);
  };
  auto node = [&](u16* x, int n, int i, int F,
                  const u16* Wf0, const u16* Wf1, u16* oF0, u16* oF1){
    if (F == 2)
      mlp_kernel<M_NODE, 2, 0><<<grd(n), 256, 0, stream>>>(
        c_nW0 + (size_t)i*256*HD, c_nW0 + (size_t)i*256*HD + KS, c_nW1 + (size_t)i*HD*HD,
        nb0 + i*HD, nb1 + i*HD, nullptr, ng + i*HD, nbt + i*HD,
        x, nullptr, nullptr, nullptr, nullptr, rowptr, ea_s, nullptr,
        x, n, nullptr, nullptr, nullptr, nullptr, Wf0, Wf1, oF0, oF1, NC,
        nullptr, nullptr);
    else if (F == 1)
      mlp_kernel<M_NODE, 1, 0><<<grd(n), 256, 0, stream>>>(
        c_nW0 + (size_t)i*256*HD, c_nW0 + (size_t)i*256*HD + KS, c_nW1 + (size_t)i*HD*HD,
        nb0 + i*HD, nb1 + i*HD, nullptr, ng + i*HD, nbt + i*HD,
        x, nullptr, nullptr, nullptr, nullptr, rowptr, ea_s, nullptr,
        x, n, nullptr, nullptr, nullptr, nullptr, Wf0, nullptr, oF0, nullptr, NC,
        nullptr, nullptr);
    else
      mlp_kernel<M_NODE, 0, 0><<<grd(n), 256, 0, stream>>>(
        c_nW0 + (size_t)i*256*HD, c_nW0 + (size_t)i*256*HD + KS, c_nW1 + (size_t)i*HD*HD,
        nb0 + i*HD, nb1 + i*HD, nullptr, ng + i*HD, nbt + i*HD,
        x, nullptr, nullptr, nullptr, nullptr, rowptr, ea_s, nullptr,
        x, n, nullptr, nullptr, nullptr, nullptr, nullptr, nullptr, nullptr, nullptr, 0,
        nullptr, nullptr);
  };

  // ---- pass 1 on xa ----
  lin2_kernel<<<grd(NC), 256, 0, stream>>>(eslice(0,0), eslice(0,1), xa, P, Q, NC);
  edgeP(0);                                                    // gathers + converts ea inline
  node(xa, NC, 0, 2, eslice(1,0), eslice(1,1), P, Q);          // next-iter P,Q
  edge(1);
  node(xa, NC, 1, 1, c_uW0 + KS, nullptr, XU, nullptr);        // XU = xa @ uW0b

  // ---- decoder (fused DEC1+DEC2), fuses pass-2 first P,Q ----
  mlp_kernel<M_DEC12, 2, 0><<<grd(NF), 256, 0, stream>>>(
    c_dW1, c_uW0, c_uW1,
    db1, ub0, ub1, ug, ubt,
    nullptr, XU, nullptr, nullptr, nullptr, nullptr, nullptr, clus,
    xb, NF, dW0, db0, pos_c, pos_f,
    eslice(0,0), eslice(0,1), P, Q, NC,
    nullptr, nullptr);

  // ---- pass 2 on xb ----
  edge(0);
  node(xb, NF, 0, 2, eslice(1,0), eslice(1,1), P, Q);
  edge(1);
  node(xb, NF, 1, 0, nullptr, nullptr, nullptr, nullptr);

  float* out = (float*)d_out;
  outhead_kernel<<<(NF + 3) / 4, 256, 0, stream>>>(xb, oW, ob, out);
  idxcopy_kernel<<<(2 * ECNT + 255) / 256, 256, 0, stream>>>(ei, out + (size_t)NF * OUTD);
}

// Round 16
// 803.845 us; speedup vs baseline: 1.0022x; 1.0022x over previous
//
#include <hip/hip_runtime.h>

// Decoder_48378511622552 — CSR-sorted, bf16, K=128 MFMA fused GNN decoder (gfx950)
// Round 16: EDGE isolated into its own kernel (R15 lean epilogue, 16KB LDS, VGPR~40);
// mlp_kernel is NODE/DEC12-only (restores R14 codegen — rule-19 cross-instantiation
// perturbation removed). Best-of-both combination.

#define HD   128
#define NC   50000
#define NF   150000
#define ECNT 400000
#define OUTD 3
#define SCB  512
#define NB_SCAN ((NF + SCB - 1) / SCB)   // 293

typedef unsigned short u16;
typedef unsigned int   u32;
typedef short bf16x8 __attribute__((ext_vector_type(8)));
typedef float f32x4  __attribute__((ext_vector_type(4)));

__device__ __forceinline__ float bf2f(u32 u){ return __uint_as_float(u << 16); }
__device__ __forceinline__ u32 cvtpk(float a, float b){   // lo = bf16(a), hi = bf16(b)
  u32 r; asm("v_cvt_pk_bf16_f32 %0, %1, %2" : "=v"(r) : "v"(a), "v"(b)); return r;
}
__device__ __forceinline__ u16 f2bf(float f){ return (u16)cvtpk(f, f); }
__device__ __forceinline__ u32 addpk(u32 a, u32 b){
  return cvtpk(bf2f(a & 0xffffu) + bf2f(b & 0xffffu),
               __uint_as_float(a & 0xffff0000u) + __uint_as_float(b & 0xffff0000u));
}
__device__ __forceinline__ float eluf(float x){ return x > 0.f ? x : __expf(x) - 1.f; }
// swizzle for bf16 [32][256B] tiles
__device__ __forceinline__ int SW(int row, int byte){ return row * 256 + (byte ^ ((row & 7) << 4)); }

// ---------------- prep kernels ----------------

__global__ void prep_all_kernel(const float* __restrict__ eW0, const float* __restrict__ eW1,
                                const float* __restrict__ nW0, const float* __restrict__ nW1,
                                const float* __restrict__ uW0, const float* __restrict__ uW1,
                                const float* __restrict__ dW1,
                                u16* c_eW0, u16* c_eW1, u16* c_nW0, u16* c_nW1,
                                u16* c_uW0, u16* c_uW1, u16* c_dW1)
{
  int b = blockIdx.x;
  const float* src; u16* dst; int kb;
  if      (b <  384){ src = eW0; dst = c_eW0; kb = b * 2; }          // K=768 (2 mats)
  else if (b <  512){ src = eW1; dst = c_eW1; kb = (b - 384) * 2; }  // K=256
  else if (b <  768){ src = nW0; dst = c_nW0; kb = (b - 512) * 2; }  // K=512
  else if (b <  896){ src = nW1; dst = c_nW1; kb = (b - 768) * 2; }  // K=256
  else if (b < 1024){ src = uW0; dst = c_uW0; kb = (b - 896) * 2; }  // K=256
  else if (b < 1088){ src = uW1; dst = c_uW1; kb = (b - 1024) * 2; } // K=128
  else              { src = dW1; dst = c_dW1; kb = (b - 1088) * 2; } // K=128
  int t = threadIdx.x;
  int k = kb + (t >> 7), j = t & 127;
  dst[(((k >> 3) * HD + j) << 3) + (k & 7)] = f2bf(src[k * HD + j]);
}

__global__ void f32_to_bf16_vec(const float* __restrict__ in, u16* __restrict__ out, int n8){
  int i = blockIdx.x * blockDim.x + threadIdx.x;
  if (i >= n8) return;
  float4 f0 = ((const float4*)in)[i * 2];
  float4 f1 = ((const float4*)in)[i * 2 + 1];
  ((uint4*)out)[i] = make_uint4(cvtpk(f0.x,f0.y), cvtpk(f0.z,f0.w), cvtpk(f1.x,f1.y), cvtpk(f1.z,f1.w));
}

__global__ void deg_kernel(const int* __restrict__ ei, int* __restrict__ deg){
  int e = blockIdx.x * blockDim.x + threadIdx.x;
  if (e < ECNT) atomicAdd(&deg[ei[ECNT + e]], 1);
}

__global__ void scanA_kernel(const int* __restrict__ deg, int* __restrict__ part){
  __shared__ int s[SCB];
  int t = threadIdx.x, i = blockIdx.x * SCB + t;
  s[t] = (i < NF) ? deg[i] : 0;
  __syncthreads();
  for (int off = SCB/2; off; off >>= 1){ if (t < off) s[t] += s[t + off]; __syncthreads(); }
  if (t == 0) part[blockIdx.x] = s[0];
}

__global__ void scanB_kernel(int* __restrict__ part){
  __shared__ int s[SCB];
  int t = threadIdx.x;
  int v = (t < NB_SCAN) ? part[t] : 0;
  s[t] = v; __syncthreads();
  for (int off = 1; off < SCB; off <<= 1){
    int x = (t >= off) ? s[t - off] : 0;
    __syncthreads(); s[t] += x; __syncthreads();
  }
  if (t < NB_SCAN) part[t] = s[t] - v;   // exclusive
}

__global__ void scanC_kernel(const int* __restrict__ deg, const int* __restrict__ part,
                             int* __restrict__ rowptr){
  __shared__ int s[SCB];
  int t = threadIdx.x, i = blockIdx.x * SCB + t;
  int v = (i < NF) ? deg[i] : 0;
  s[t] = v; __syncthreads();
  for (int off = 1; off < SCB; off <<= 1){
    int x = (t >= off) ? s[t - off] : 0;
    __syncthreads(); s[t] += x; __syncthreads();
  }
  int excl = part[blockIdx.x] + s[t] - v;
  if (i < NF) rowptr[i] = excl;
  if (i == NF - 1) rowptr[NF] = excl + v;
}

__global__ void build_perm_kernel(const int* __restrict__ ei, int* __restrict__ cursor,
                                  int* __restrict__ perm, int* __restrict__ esrc,
                                  int* __restrict__ edst){
  int e = blockIdx.x * blockDim.x + threadIdx.x;
  if (e >= ECNT) return;
  int sI = ei[e], d = ei[ECNT + e];
  int p = atomicAdd(&cursor[d], 1);
  perm[p] = e; esrc[p] = sI; edst[p] = d;
}

// ---------------- standalone LIN2: oA = x@Wa, oB = x@Wb ----------------
__global__ __launch_bounds__(256, 4)
void lin2_kernel(const u16* __restrict__ Wa, const u16* __restrict__ Wb,
                 const u16* __restrict__ x, u16* __restrict__ oA, u16* __restrict__ oB,
                 int n_rows)
{
  __shared__ __align__(16) char ldsA[32 * 256];
  const int tid = threadIdx.x, lane = tid & 63, wid = tid >> 6;
  const int ln = lane & 15, kq = lane >> 4, ncol = wid * 32;

  const int row0 = blockIdx.x << 5;
  #pragma unroll
  for (int c = 0; c < 2; ++c){
    int i = tid + c * 256, row = i >> 4, kk = i & 15, rg = row0 + row;
    if (rg < n_rows)
      *(uint4*)(ldsA + SW(row, kk * 16)) = *(const uint4*)(x + (((size_t)rg) << 7) + (kk << 3));
  }
  __syncthreads();
  bf16x8 af[4][2];
  #pragma unroll
  for (int k0 = 0; k0 < 4; ++k0){
    af[k0][0] = *(const bf16x8*)(ldsA + SW(ln,      k0 * 64 + (kq << 4)));
    af[k0][1] = *(const bf16x8*)(ldsA + SW(16 + ln, k0 * 64 + (kq << 4)));
  }
  const u16* Ws[2] = {Wa, Wb};
  u16*       Os[2] = {oA, oB};
  const f32x4 zz = {0.f, 0.f, 0.f, 0.f};
  #pragma unroll
  for (int w = 0; w < 2; ++w){
    const u16* wp = Ws[w];
    asm volatile("" : "+v"(wp));
    uint4 bfr[4][2];
    #pragma unroll
    for (int k0 = 0; k0 < 4; ++k0)
      #pragma unroll
      for (int nt = 0; nt < 2; ++nt)
        bfr[k0][nt] = *(const uint4*)(wp + (((size_t)((k0*4 + kq)*HD + ncol + nt*16 + ln)) << 3));
    f32x4 cc[2][2] = {{zz, zz}, {zz, zz}};
    #pragma unroll
    for (int k0 = 0; k0 < 4; ++k0){
      bf16x8 w0 = __builtin_bit_cast(bf16x8, bfr[k0][0]);
      bf16x8 w1 = __builtin_bit_cast(bf16x8, bfr[k0][1]);
      cc[0][0] = __builtin_amdgcn_mfma_f32_16x16x32_bf16(af[k0][0], w0, cc[0][0], 0, 0, 0);
      cc[0][1] = __builtin_amdgcn_mfma_f32_16x16x32_bf16(af[k0][0], w1, cc[0][1], 0, 0, 0);
      cc[1][0] = __builtin_amdgcn_mfma_f32_16x16x32_bf16(af[k0][1], w0, cc[1][0], 0, 0, 0);
      cc[1][1] = __builtin_amdgcn_mfma_f32_16x16x32_bf16(af[k0][1], w1, cc[1][1], 0, 0, 0);
    }
    u16* op = Os[w];
    #pragma unroll
    for (int mi = 0; mi < 2; ++mi)
      #pragma unroll
      for (int nt = 0; nt < 2; ++nt)
        #pragma unroll
        for (int r = 0; r < 4; ++r){
          int rg = row0 + mi * 16 + kq * 4 + r;
          if (rg < n_rows) op[(size_t)rg * HD + ncol + nt * 16 + ln] = f2bf(cc[mi][nt][r]);
        }
  }
}

// ---------------- standalone EDGE kernel (isolated codegen) ----------------
// A=ea; h=elu(A@W0 + P[src]+Q[dst] + b0); cf=h@W1; out = LN(cf+b1 + A)
// PERM=1: gather A rows from f32 eaf via perm, convert inline.
// Lean LDS-roundtrip epilogue (VGPR~40, 16KB LDS).
template<int PERM>
__global__ __launch_bounds__(256, 4)
void edge_kernel(const u16* __restrict__ W0c, const u16* __restrict__ W1c,
                 const float* __restrict__ b0, const float* __restrict__ b1,
                 const float* __restrict__ gw, const float* __restrict__ bw,
                 const u16* __restrict__ tabA, const u16* __restrict__ addP,
                 const u16* __restrict__ addQ,
                 const int* __restrict__ esrc, const int* __restrict__ edst,
                 u16* __restrict__ outp,
                 const int* __restrict__ permp, const float* __restrict__ eaf)
{
  __shared__ __align__(16) char ldsA [32 * 256];   // ea tile (residual source)
  __shared__ __align__(16) char ldsPQ[32 * 256];   // addend -> h -> r

  const int tid  = threadIdx.x;
  const int lane = tid & 63;
  const int wid  = tid >> 6;
  const int ln   = lane & 15, kq = lane >> 4;
  const int ncol = wid * 32;

  bf16x8 b1f[4][2];
  #pragma unroll
  for (int k0 = 0; k0 < 4; ++k0)
    #pragma unroll
    for (int nt = 0; nt < 2; ++nt)
      b1f[k0][nt] = *(const bf16x8*)(W0c + (((size_t)((k0*4 + kq)*HD + ncol + nt*16 + ln)) << 3));

  float b0v[2], b1v[2];
  #pragma unroll
  for (int nt = 0; nt < 2; ++nt){
    int col = ncol + nt*16 + ln;
    b0v[nt] = b0[col]; b1v[nt] = b1[col];
  }
  float gl0 = gw[lane], gl1 = gw[64 + lane], bt0 = bw[lane], bt1 = bw[64 + lane];

  const int row0 = blockIdx.x << 5;
  const f32x4 zz = {0.f, 0.f, 0.f, 0.f};
  f32x4 cf[2][2];

  // ---- stage: ea -> ldsA (PERM: gather f32 + convert), P+Q -> ldsPQ ----
  #pragma unroll
  for (int c = 0; c < 2; ++c){
    int i = tid + c * 256, row = i >> 4, kk = i & 15, rg = row0 + row;   // ECNT%32==0
    uint4 va;
    if constexpr (PERM){
      int e = permp[rg];
      const float4* src = (const float4*)(eaf + (((size_t)e) << 7) + (kk << 3));
      float4 fa = src[0], fb = src[1];
      va = make_uint4(cvtpk(fa.x,fa.y), cvtpk(fa.z,fa.w), cvtpk(fb.x,fb.y), cvtpk(fb.z,fb.w));
    } else {
      va = *(const uint4*)(tabA + (((size_t)rg) << 7) + (kk << 3));
    }
    *(uint4*)(ldsA + SW(row, kk * 16)) = va;
    int sI = esrc[rg], dI = edst[rg];
    uint4 p = *(const uint4*)(addP + (((size_t)sI) << 7) + (kk << 3));
    uint4 q = *(const uint4*)(addQ + (((size_t)dI) << 7) + (kk << 3));
    *(uint4*)(ldsPQ + SW(row, kk * 16)) =
        make_uint4(addpk(p.x,q.x), addpk(p.y,q.y), addpk(p.z,q.z), addpk(p.w,q.w));
  }
  __syncthreads();   // A
  // GEMM1
  cf[0][0]=zz; cf[0][1]=zz; cf[1][0]=zz; cf[1][1]=zz;
  #pragma unroll
  for (int k0 = 0; k0 < 4; ++k0){
    bf16x8 a0 = *(const bf16x8*)(ldsA + SW(ln,      k0 * 64 + (kq << 4)));
    bf16x8 a1 = *(const bf16x8*)(ldsA + SW(16 + ln, k0 * 64 + (kq << 4)));
    cf[0][0] = __builtin_amdgcn_mfma_f32_16x16x32_bf16(a0, b1f[k0][0], cf[0][0], 0, 0, 0);
    cf[0][1] = __builtin_amdgcn_mfma_f32_16x16x32_bf16(a0, b1f[k0][1], cf[0][1], 0, 0, 0);
    cf[1][0] = __builtin_amdgcn_mfma_f32_16x16x32_bf16(a1, b1f[k0][0], cf[1][0], 0, 0, 0);
    cf[1][1] = __builtin_amdgcn_mfma_f32_16x16x32_bf16(a1, b1f[k0][1], cf[1][1], 0, 0, 0);
  }
  // h = elu(cf + pq + b0) -> ldsPQ in place (same-thread RMW at C positions)
  #pragma unroll
  for (int mi = 0; mi < 2; ++mi)
    #pragma unroll
    for (int nt = 0; nt < 2; ++nt)
      #pragma unroll
      for (int r = 0; r < 4; ++r){
        int row = mi * 16 + kq * 4 + r, col = ncol + nt * 16 + ln;
        u16* pp = (u16*)(ldsPQ + SW(row, col * 2));
        *pp = f2bf(eluf(cf[mi][nt][r] + bf2f(*pp) + b0v[nt]));
      }
  __syncthreads();   // B
  // GEMM2
  {
    const u16* w1p = W1c;
    asm volatile("" : "+v"(w1p));
    uint4 b2r[4][2];
    #pragma unroll
    for (int k0 = 0; k0 < 4; ++k0)
      #pragma unroll
      for (int nt = 0; nt < 2; ++nt)
        b2r[k0][nt] = *(const uint4*)(w1p + (((size_t)((k0*4 + kq)*HD + ncol + nt*16 + ln)) << 3));
    cf[0][0]=zz; cf[0][1]=zz; cf[1][0]=zz; cf[1][1]=zz;
    #pragma unroll
    for (int k0 = 0; k0 < 4; ++k0){
      bf16x8 a0 = *(const bf16x8*)(ldsPQ + SW(ln,      k0 * 64 + (kq << 4)));
      bf16x8 a1 = *(const bf16x8*)(ldsPQ + SW(16 + ln, k0 * 64 + (kq << 4)));
      bf16x8 w0 = __builtin_bit_cast(bf16x8, b2r[k0][0]);
      bf16x8 w1 = __builtin_bit_cast(bf16x8, b2r[k0][1]);
      cf[0][0] = __builtin_amdgcn_mfma_f32_16x16x32_bf16(a0, w0, cf[0][0], 0, 0, 0);
      cf[0][1] = __builtin_amdgcn_mfma_f32_16x16x32_bf16(a0, w1, cf[0][1], 0, 0, 0);
      cf[1][0] = __builtin_amdgcn_mfma_f32_16x16x32_bf16(a1, w0, cf[1][0], 0, 0, 0);
      cf[1][1] = __builtin_amdgcn_mfma_f32_16x16x32_bf16(a1, w1, cf[1][1], 0, 0, 0);
    }
  }
  __syncthreads();   // B2: h reads done
  // r = cf + b1 -> ldsPQ (bf16)
  #pragma unroll
  for (int mi = 0; mi < 2; ++mi)
    #pragma unroll
    for (int nt = 0; nt < 2; ++nt)
      #pragma unroll
      for (int r = 0; r < 4; ++r){
        int row = mi * 16 + kq * 4 + r, col = ncol + nt * 16 + ln;
        *(u16*)(ldsPQ + SW(row, col * 2)) = f2bf(cf[mi][nt][r] + b1v[nt]);
      }
  __syncthreads();   // C
  // LN: wave-per-row, residual from ldsA, 32-lane butterfly
  #pragma unroll
  for (int rr = 0; rr < 8; ++rr){
    int e = wid * 8 + rr, rg = row0 + e;
    float v0 = bf2f(*(const u16*)(ldsPQ + SW(e, lane * 2)));
    float v1 = bf2f(*(const u16*)(ldsPQ + SW(e, (64 + lane) * 2)));
    v0 += bf2f(*(const u16*)(ldsA + SW(e, lane * 2)));
    v1 += bf2f(*(const u16*)(ldsA + SW(e, (64 + lane) * 2)));
    float s = v0 + v1, q = v0 * v0 + v1 * v1;
    #pragma unroll
    for (int o = 32; o; o >>= 1){ s += __shfl_xor(s, o); q += __shfl_xor(q, o); }
    float mu  = s * (1.f / 128.f);
    float var = q * (1.f / 128.f) - mu * mu;
    float rs  = rsqrtf(var + 1e-5f);
    float y0 = (v0 - mu) * rs * gl0 + bt0;
    float y1 = (v1 - mu) * rs * gl1 + bt1;
    outp[(((size_t)rg) << 7) + lane]      = f2bf(y0);
    outp[(((size_t)rg) << 7) + 64 + lane] = f2bf(y1);
  }
}

// ---------------- unified fused K=128 MFMA MLP (NODE / DEC12 only) ----------------
enum { M_NODE = 1, M_DEC12 = 2 };

// NODE : cf1=x@W0 (+ act: CSR-mean(ea)@W1); h=elu(cf1+b0); cf=h@W2; out = LN(cf+b1 + x)
// DEC12: h1=elu(delta@dW0+db0); eac=elu(h1@W0+b0); h=elu(eac@W1 + XU[clus] + b1);
//        cf=h@W2;                                              out = LN(elu(cf+b2) + eac)
// FUSE>0: after LN store, compute oF[w] = out_tile @ Wf[w] for blocks row0 < fuse_n.
template<int MODE, int FUSE>
__global__ __launch_bounds__(256, 4)
void mlp_kernel(const u16* __restrict__ W0c, const u16* __restrict__ W1c,
                const u16* __restrict__ W2c,
                const float* __restrict__ b0, const float* __restrict__ b1,
                const float* __restrict__ b2,
                const float* __restrict__ gw, const float* __restrict__ bw,
                const u16* __restrict__ tabA, const u16* __restrict__ addP,
                const int* __restrict__ rowptr, const u16* __restrict__ eatab,
                const int* __restrict__ clus,
                u16* __restrict__ outp, int n_rows,
                const float* __restrict__ dW0, const float* __restrict__ db0,
                const float* __restrict__ pos_c, const float* __restrict__ pos_f,
                const u16* __restrict__ Wf0, const u16* __restrict__ Wf1,
                u16* __restrict__ oF0, u16* __restrict__ oF1, int fuse_n)
{
  constexpr bool ELU2 = (MODE == M_DEC12);

  __shared__ __align__(16) char  ldsA [32 * 256];   // x/eac tile (residual source)
  __shared__ __align__(16) char  ldsPQ[32 * 256];   // addend/mean -> h
  __shared__ float ldsSQ[32 * 8];                   // per-row wave partials {s,q} x4
  __shared__ float ldsM [32 * 2];                   // per-row {mu, rs}

  const int tid  = threadIdx.x;
  const int lane = tid & 63;
  const int wid  = tid >> 6;
  const int ln   = lane & 15, kq = lane >> 4;
  const int ncol = wid * 32;

  bf16x8 b1f[4][2];
  #pragma unroll
  for (int k0 = 0; k0 < 4; ++k0)
    #pragma unroll
    for (int nt = 0; nt < 2; ++nt)
      b1f[k0][nt] = *(const bf16x8*)(W0c + (((size_t)((k0*4 + kq)*HD + ncol + nt*16 + ln)) << 3));

  float b0v[2], b1v[2], bfin[2], gv[2], btv[2];
  #pragma unroll
  for (int nt = 0; nt < 2; ++nt){
    int col = ncol + nt*16 + ln;
    b0v[nt] = b0[col]; b1v[nt] = b1[col];
    bfin[nt] = (MODE == M_DEC12) ? b2[col] : b1v[nt];
    gv[nt] = gw[col]; btv[nt] = bw[col];
  }

  const int row0 = blockIdx.x << 5;
  const f32x4 zz = {0.f, 0.f, 0.f, 0.f};
  f32x4 cf[2][2];

  if constexpr (MODE == M_NODE){
    // ---- stage: x -> ldsA ; act: CSR mean -> ldsPQ ----
    #pragma unroll
    for (int c = 0; c < 2; ++c){
      int i = tid + c * 256, row = i >> 4, kk = i & 15, rg = row0 + row;
      if (rg < n_rows)
        *(uint4*)(ldsA + SW(row, kk * 16)) =
            *(const uint4*)(tabA + (((size_t)rg) << 7) + (kk << 3));
    }
    const bool act = (row0 < NC);   // rows >= NC have degree 0 (block-uniform)
    if (act){
      for (int s = 0; s < 8; ++s){
        int nd = wid * 8 + s, rg = row0 + nd;
        if (rg < n_rows){
          int rp0 = rowptr[rg], rp1 = rowptr[rg + 1];
          float s0 = 0.f, s1 = 0.f, t0 = 0.f, t1 = 0.f;
          int i2 = rp0;
          for (; i2 + 3 < rp1; i2 += 4){
            u32 ua = *(const u32*)(eatab + (((size_t) i2     ) << 7) + (lane << 1));
            u32 ub = *(const u32*)(eatab + (((size_t)(i2 + 1)) << 7) + (lane << 1));
            u32 uc = *(const u32*)(eatab + (((size_t)(i2 + 2)) << 7) + (lane << 1));
            u32 ud = *(const u32*)(eatab + (((size_t)(i2 + 3)) << 7) + (lane << 1));
            s0 += bf2f(ua & 0xffffu) + bf2f(ub & 0xffffu);
            s1 += bf2f(ua >> 16)     + bf2f(ub >> 16);
            t0 += bf2f(uc & 0xffffu) + bf2f(ud & 0xffffu);
            t1 += bf2f(uc >> 16)     + bf2f(ud >> 16);
          }
          for (; i2 < rp1; ++i2){
            u32 ua = *(const u32*)(eatab + (((size_t)i2) << 7) + (lane << 1));
            s0 += bf2f(ua & 0xffffu); s1 += bf2f(ua >> 16);
          }
          s0 += t0; s1 += t1;
          int dg = rp1 - rp0;
          float rd = 1.f / (float)(dg > 0 ? dg : 1);
          *(u32*)(ldsPQ + SW(nd, lane << 2)) = cvtpk(s0 * rd, s1 * rd);
        }
      }
    }
    __syncthreads();   // A
    // GEMM1: cf = x @ nW0a
    cf[0][0]=zz; cf[0][1]=zz; cf[1][0]=zz; cf[1][1]=zz;
    #pragma unroll
    for (int k0 = 0; k0 < 4; ++k0){
      bf16x8 a0 = *(const bf16x8*)(ldsA + SW(ln,      k0 * 64 + (kq << 4)));
      bf16x8 a1 = *(const bf16x8*)(ldsA + SW(16 + ln, k0 * 64 + (kq << 4)));
      cf[0][0] = __builtin_amdgcn_mfma_f32_16x16x32_bf16(a0, b1f[k0][0], cf[0][0], 0, 0, 0);
      cf[0][1] = __builtin_amdgcn_mfma_f32_16x16x32_bf16(a0, b1f[k0][1], cf[0][1], 0, 0, 0);
      cf[1][0] = __builtin_amdgcn_mfma_f32_16x16x32_bf16(a1, b1f[k0][0], cf[1][0], 0, 0, 0);
      cf[1][1] = __builtin_amdgcn_mfma_f32_16x16x32_bf16(a1, b1f[k0][1], cf[1][1], 0, 0, 0);
    }
    if (act){
      // cf += mean @ nW0b
      const u16* wbp = W1c;
      asm volatile("" : "+v"(wbp));
      uint4 bbr[4][2];
      #pragma unroll
      for (int k0 = 0; k0 < 4; ++k0)
        #pragma unroll
        for (int nt = 0; nt < 2; ++nt)
          bbr[k0][nt] = *(const uint4*)(wbp + (((size_t)((k0*4 + kq)*HD + ncol + nt*16 + ln)) << 3));
      #pragma unroll
      for (int k0 = 0; k0 < 4; ++k0){
        bf16x8 a0 = *(const bf16x8*)(ldsPQ + SW(ln,      k0 * 64 + (kq << 4)));
        bf16x8 a1 = *(const bf16x8*)(ldsPQ + SW(16 + ln, k0 * 64 + (kq << 4)));
        bf16x8 w0 = __builtin_bit_cast(bf16x8, bbr[k0][0]);
        bf16x8 w1 = __builtin_bit_cast(bf16x8, bbr[k0][1]);
        cf[0][0] = __builtin_amdgcn_mfma_f32_16x16x32_bf16(a0, w0, cf[0][0], 0, 0, 0);
        cf[0][1] = __builtin_amdgcn_mfma_f32_16x16x32_bf16(a0, w1, cf[0][1], 0, 0, 0);
        cf[1][0] = __builtin_amdgcn_mfma_f32_16x16x32_bf16(a1, w0, cf[1][0], 0, 0, 0);
        cf[1][1] = __builtin_amdgcn_mfma_f32_16x16x32_bf16(a1, w1, cf[1][1], 0, 0, 0);
      }
    }
    __syncthreads();   // B: mean reads done
    // h = elu(cf + b0) -> ldsPQ (C positions)
    #pragma unroll
    for (int mi = 0; mi < 2; ++mi)
      #pragma unroll
      for (int nt = 0; nt < 2; ++nt)
        #pragma unroll
        for (int r = 0; r < 4; ++r){
          int row = mi * 16 + kq * 4 + r, col = ncol + nt * 16 + ln;
          *(u16*)(ldsPQ + SW(row, col * 2)) = f2bf(eluf(cf[mi][nt][r] + b0v[nt]));
        }
    __syncthreads();   // C
    // GEMM2: cf = h @ nW1
    {
      const u16* w2p = W2c;
      asm volatile("" : "+v"(w2p));
      uint4 b3r[4][2];
      #pragma unroll
      for (int k0 = 0; k0 < 4; ++k0)
        #pragma unroll
        for (int nt = 0; nt < 2; ++nt)
          b3r[k0][nt] = *(const uint4*)(w2p + (((size_t)((k0*4 + kq)*HD + ncol + nt*16 + ln)) << 3));
      cf[0][0]=zz; cf[0][1]=zz; cf[1][0]=zz; cf[1][1]=zz;
      #pragma unroll
      for (int k0 = 0; k0 < 4; ++k0){
        bf16x8 a0 = *(const bf16x8*)(ldsPQ + SW(ln,      k0 * 64 + (kq << 4)));
        bf16x8 a1 = *(const bf16x8*)(ldsPQ + SW(16 + ln, k0 * 64 + (kq << 4)));
        bf16x8 w0 = __builtin_bit_cast(bf16x8, b3r[k0][0]);
        bf16x8 w1 = __builtin_bit_cast(bf16x8, b3r[k0][1]);
        cf[0][0] = __builtin_amdgcn_mfma_f32_16x16x32_bf16(a0, w0, cf[0][0], 0, 0, 0);
        cf[0][1] = __builtin_amdgcn_mfma_f32_16x16x32_bf16(a0, w1, cf[0][1], 0, 0, 0);
        cf[1][0] = __builtin_amdgcn_mfma_f32_16x16x32_bf16(a1, w0, cf[1][0], 0, 0, 0);
        cf[1][1] = __builtin_amdgcn_mfma_f32_16x16x32_bf16(a1, w1, cf[1][1], 0, 0, 0);
      }
    }
  } else { // M_DEC12
    // ---- stage: h1 = elu(delta@dW0+db0) -> ldsA ; XU[clus] -> ldsPQ ----
    #pragma unroll
    for (int c = 0; c < 2; ++c){
      int i = tid + c * 256, row = i >> 4, c8 = i & 15, rg = row0 + row;
      if (rg < n_rows){
        int cl = clus[rg];
        *(uint4*)(ldsPQ + SW(row, c8 * 16)) =
            *(const uint4*)(addP + (((size_t)cl) << 7) + (c8 << 3));
        float d0 = pos_c[cl * 2]     - pos_f[rg * 2];
        float d1 = pos_c[cl * 2 + 1] - pos_f[rg * 2 + 1];
        u32 wq[4];
        #pragma unroll
        for (int q = 0; q < 4; ++q){
          int cc = c8 * 8 + q * 2;
          float va = eluf(fmaf(d0, dW0[cc],     fmaf(d1, dW0[HD + cc],     db0[cc])));
          float vb = eluf(fmaf(d0, dW0[cc + 1], fmaf(d1, dW0[HD + cc + 1], db0[cc + 1])));
          wq[q] = cvtpk(va, vb);
        }
        *(uint4*)(ldsA + SW(row, c8 * 16)) = make_uint4(wq[0], wq[1], wq[2], wq[3]);
      }
    }
    __syncthreads();   // A
    // GEMM1: cf = h1 @ dW1
    cf[0][0]=zz; cf[0][1]=zz; cf[1][0]=zz; cf[1][1]=zz;
    #pragma unroll
    for (int k0 = 0; k0 < 4; ++k0){
      bf16x8 a0 = *(const bf16x8*)(ldsA + SW(ln,      k0 * 64 + (kq << 4)));
      bf16x8 a1 = *(const bf16x8*)(ldsA + SW(16 + ln, k0 * 64 + (kq << 4)));
      cf[0][0] = __builtin_amdgcn_mfma_f32_16x16x32_bf16(a0, b1f[k0][0], cf[0][0], 0, 0, 0);
      cf[0][1] = __builtin_amdgcn_mfma_f32_16x16x32_bf16(a0, b1f[k0][1], cf[0][1], 0, 0, 0);
      cf[1][0] = __builtin_amdgcn_mfma_f32_16x16x32_bf16(a1, b1f[k0][0], cf[1][0], 0, 0, 0);
      cf[1][1] = __builtin_amdgcn_mfma_f32_16x16x32_bf16(a1, b1f[k0][1], cf[1][1], 0, 0, 0);
    }
    __syncthreads();   // B: h1 reads done
    // eac = elu(cf + b0) -> ldsA (C positions)
    #pragma unroll
    for (int mi = 0; mi < 2; ++mi)
      #pragma unroll
      for (int nt = 0; nt < 2; ++nt)
        #pragma unroll
        for (int r = 0; r < 4; ++r){
          int row = mi * 16 + kq * 4 + r, col = ncol + nt * 16 + ln;
          *(u16*)(ldsA + SW(row, col * 2)) = f2bf(eluf(cf[mi][nt][r] + b0v[nt]));
        }
    __syncthreads();   // C: eac visible
    // GEMM2: cf = eac @ uW0a ; h = elu(cf + XU + b1) -> ldsPQ in place
    {
      const u16* w1p = W1c;
      asm volatile("" : "+v"(w1p));
      uint4 b2r[4][2];
      #pragma unroll
      for (int k0 = 0; k0 < 4; ++k0)
        #pragma unroll
        for (int nt = 0; nt < 2; ++nt)
          b2r[k0][nt] = *(const uint4*)(w1p + (((size_t)((k0*4 + kq)*HD + ncol + nt*16 + ln)) << 3));
      cf[0][0]=zz; cf[0][1]=zz; cf[1][0]=zz; cf[1][1]=zz;
      #pragma unroll
      for (int k0 = 0; k0 < 4; ++k0){
        bf16x8 a0 = *(const bf16x8*)(ldsA + SW(ln,      k0 * 64 + (kq << 4)));
        bf16x8 a1 = *(const bf16x8*)(ldsA + SW(16 + ln, k0 * 64 + (kq << 4)));
        bf16x8 w0 = __builtin_bit_cast(bf16x8, b2r[k0][0]);
        bf16x8 w1 = __builtin_bit_cast(bf16x8, b2r[k0][1]);
        cf[0][0] = __builtin_amdgcn_mfma_f32_16x16x32_bf16(a0, w0, cf[0][0], 0, 0, 0);
        cf[0][1] = __builtin_amdgcn_mfma_f32_16x16x32_bf16(a0, w1, cf[0][1], 0, 0, 0);
        cf[1][0] = __builtin_amdgcn_mfma_f32_16x16x32_bf16(a1, w0, cf[1][0], 0, 0, 0);
        cf[1][1] = __builtin_amdgcn_mfma_f32_16x16x32_bf16(a1, w1, cf[1][1], 0, 0, 0);
      }
      #pragma unroll
      for (int mi = 0; mi < 2; ++mi)
        #pragma unroll
        for (int nt = 0; nt < 2; ++nt)
          #pragma unroll
          for (int r = 0; r < 4; ++r){
            int row = mi * 16 + kq * 4 + r, col = ncol + nt * 16 + ln;
            u16* pp = (u16*)(ldsPQ + SW(row, col * 2));
            *pp = f2bf(eluf(cf[mi][nt][r] + bf2f(*pp) + b1v[nt]));
          }
    }
    __syncthreads();   // D
    // GEMM3: cf = h @ uW1
    {
      const u16* w2p = W2c;
      asm volatile("" : "+v"(w2p));
      uint4 b3r[4][2];
      #pragma unroll
      for (int k0 = 0; k0 < 4; ++k0)
        #pragma unroll
        for (int nt = 0; nt < 2; ++nt)
          b3r[k0][nt] = *(const uint4*)(w2p + (((size_t)((k0*4 + kq)*HD + ncol + nt*16 + ln)) << 3));
      cf[0][0]=zz; cf[0][1]=zz; cf[1][0]=zz; cf[1][1]=zz;
      #pragma unroll
      for (int k0 = 0; k0 < 4; ++k0){
        bf16x8 a0 = *(const bf16x8*)(ldsPQ + SW(ln,      k0 * 64 + (kq << 4)));
        bf16x8 a1 = *(const bf16x8*)(ldsPQ + SW(16 + ln, k0 * 64 + (kq << 4)));
        bf16x8 w0 = __builtin_bit_cast(bf16x8, b3r[k0][0]);
        bf16x8 w1 = __builtin_bit_cast(bf16x8, b3r[k0][1]);
        cf[0][0] = __builtin_amdgcn_mfma_f32_16x16x32_bf16(a0, w0, cf[0][0], 0, 0, 0);
        cf[0][1] = __builtin_amdgcn_mfma_f32_16x16x32_bf16(a0, w1, cf[0][1], 0, 0, 0);
        cf[1][0] = __builtin_amdgcn_mfma_f32_16x16x32_bf16(a1, w0, cf[1][0], 0, 0, 0);
        cf[1][1] = __builtin_amdgcn_mfma_f32_16x16x32_bf16(a1, w1, cf[1][1], 0, 0, 0);
      }
    }
  }

  // ================= register-direct LN epilogue =================
  #pragma unroll
  for (int mi = 0; mi < 2; ++mi)
    #pragma unroll
    for (int nt = 0; nt < 2; ++nt)
      #pragma unroll
      for (int r = 0; r < 4; ++r){
        int row = mi * 16 + kq * 4 + r, col = ncol + nt * 16 + ln;
        float v = cf[mi][nt][r] + bfin[nt];
        if constexpr (ELU2) v = eluf(v);
        v += bf2f(*(const u16*)(ldsA + SW(row, col * 2)));
        cf[mi][nt][r] = v;
      }
  float sp[8], qp[8];
  #pragma unroll
  for (int mi = 0; mi < 2; ++mi)
    #pragma unroll
    for (int r = 0; r < 4; ++r){
      int ri = mi * 4 + r;
      float a = cf[mi][0][r], b = cf[mi][1][r];
      sp[ri] = a + b; qp[ri] = a * a + b * b;
    }
  #pragma unroll
  for (int off = 1; off < 16; off <<= 1)
    #pragma unroll
    for (int ri = 0; ri < 8; ++ri){
      sp[ri] += __shfl_xor(sp[ri], off);
      qp[ri] += __shfl_xor(qp[ri], off);
    }
  if (ln == 0){
    #pragma unroll
    for (int mi = 0; mi < 2; ++mi)
      #pragma unroll
      for (int r = 0; r < 4; ++r){
        int row = mi * 16 + kq * 4 + r;
        ldsSQ[row * 8 + wid * 2]     = sp[mi * 4 + r];
        ldsSQ[row * 8 + wid * 2 + 1] = qp[mi * 4 + r];
      }
  }
  __syncthreads();
  if (tid < 32){
    float s = ldsSQ[tid*8+0] + ldsSQ[tid*8+2] + ldsSQ[tid*8+4] + ldsSQ[tid*8+6];
    float q = ldsSQ[tid*8+1] + ldsSQ[tid*8+3] + ldsSQ[tid*8+5] + ldsSQ[tid*8+7];
    float mu  = s * (1.f / 128.f);
    float var = q * (1.f / 128.f) - mu * mu;
    ldsM[tid * 2]     = mu;
    ldsM[tid * 2 + 1] = rsqrtf(var + 1e-5f);
  }
  __syncthreads();
  #pragma unroll
  for (int mi = 0; mi < 2; ++mi)
    #pragma unroll
    for (int r = 0; r < 4; ++r){
      int row = mi * 16 + kq * 4 + r, rg = row0 + row;
      float mu = ldsM[row * 2], rs = ldsM[row * 2 + 1];
      #pragma unroll
      for (int nt = 0; nt < 2; ++nt){
        int col = ncol + nt * 16 + ln;
        float y = (cf[mi][nt][r] - mu) * rs * gv[nt] + btv[nt];
        u16 yb = f2bf(y);
        if (rg < n_rows)
          outp[(((size_t)rg) << 7) + col] = yb;
        if constexpr (FUSE > 0)
          *(u16*)(ldsA + SW(row, col * 2)) = yb;
      }
    }

  // ================= fused next-LIN GEMMs =================
  if constexpr (FUSE > 0){
    __syncthreads();
    if (row0 < fuse_n){   // block-uniform
      bf16x8 af[4][2];
      #pragma unroll
      for (int k0 = 0; k0 < 4; ++k0){
        af[k0][0] = *(const bf16x8*)(ldsA + SW(ln,      k0 * 64 + (kq << 4)));
        af[k0][1] = *(const bf16x8*)(ldsA + SW(16 + ln, k0 * 64 + (kq << 4)));
      }
      const u16* Ws[2] = {Wf0, Wf1};
      u16*       Os[2] = {oF0, oF1};
      #pragma unroll
      for (int w = 0; w < FUSE; ++w){
        const u16* wp = Ws[w];
        asm volatile("" : "+v"(wp));
        uint4 bfr[4][2];
        #pragma unroll
        for (int k0 = 0; k0 < 4; ++k0)
          #pragma unroll
          for (int nt = 0; nt < 2; ++nt)
            bfr[k0][nt] = *(const uint4*)(wp + (((size_t)((k0*4 + kq)*HD + ncol + nt*16 + ln)) << 3));
        f32x4 cc[2][2] = {{zz, zz}, {zz, zz}};
        #pragma unroll
        for (int k0 = 0; k0 < 4; ++k0){
          bf16x8 w0 = __builtin_bit_cast(bf16x8, bfr[k0][0]);
          bf16x8 w1 = __builtin_bit_cast(bf16x8, bfr[k0][1]);
          cc[0][0] = __builtin_amdgcn_mfma_f32_16x16x32_bf16(af[k0][0], w0, cc[0][0], 0, 0, 0);
          cc[0][1] = __builtin_amdgcn_mfma_f32_16x16x32_bf16(af[k0][0], w1, cc[0][1], 0, 0, 0);
          cc[1][0] = __builtin_amdgcn_mfma_f32_16x16x32_bf16(af[k0][1], w0, cc[1][0], 0, 0, 0);
          cc[1][1] = __builtin_amdgcn_mfma_f32_16x16x32_bf16(af[k0][1], w1, cc[1][1], 0, 0, 0);
        }
        u16* op = Os[w];
        #pragma unroll
        for (int mi = 0; mi < 2; ++mi)
          #pragma unroll
          for (int nt = 0; nt < 2; ++nt)
            #pragma unroll
            for (int r = 0; r < 4; ++r){
              int rg = row0 + mi * 16 + kq * 4 + r;
              if (rg < fuse_n)
                op[(size_t)rg * HD + ncol + nt * 16 + ln] = f2bf(cc[mi][nt][r]);
            }
      }
    }
  }
}

// out0 = elu(x @ oW + ob)
__global__ void outhead_kernel(const u16* __restrict__ x, const float* __restrict__ oW,
                               const float* __restrict__ ob, float* __restrict__ out){
  int row  = (blockIdx.x * blockDim.x + threadIdx.x) >> 6;
  int lane = threadIdx.x & 63;
  if (row >= NF) return;
  float x0 = bf2f(x[((size_t)row << 7) + lane]);
  float x1 = bf2f(x[((size_t)row << 7) + 64 + lane]);
  float s0 = x0 * oW[lane * 3 + 0] + x1 * oW[(64 + lane) * 3 + 0];
  float s1 = x0 * oW[lane * 3 + 1] + x1 * oW[(64 + lane) * 3 + 1];
  float s2 = x0 * oW[lane * 3 + 2] + x1 * oW[(64 + lane) * 3 + 2];
  #pragma unroll
  for (int o = 32; o; o >>= 1){
    s0 += __shfl_xor(s0, o); s1 += __shfl_xor(s1, o); s2 += __shfl_xor(s2, o);
  }
  if (lane == 0){
    out[row * 3 + 0] = eluf(s0 + ob[0]);
    out[row * 3 + 1] = eluf(s1 + ob[1]);
    out[row * 3 + 2] = eluf(s2 + ob[2]);
  }
}

__global__ void idxcopy_kernel(const int* __restrict__ ei, float* __restrict__ out){
  int i = blockIdx.x * blockDim.x + threadIdx.x;
  if (i < 2 * ECNT) out[i] = (float)ei[i];
}

extern "C" void kernel_launch(void* const* d_in, const int* in_sizes, int n_in,
                              void* d_out, int out_size, void* d_ws, size_t ws_size,
                              hipStream_t stream)
{
  const float* x_in  = (const float*)d_in[0];
  const float* ea_in = (const float*)d_in[1];
  const float* pos_c = (const float*)d_in[2];
  const float* pos_f = (const float*)d_in[3];
  const int*   ei    = (const int*)d_in[4];
  const int*   clus  = (const int*)d_in[5];
  const float* eW0 = (const float*)d_in[7];
  const float* eb0 = (const float*)d_in[8];
  const float* eW1 = (const float*)d_in[9];
  const float* eb1 = (const float*)d_in[10];
  const float* eg  = (const float*)d_in[11];
  const float* ebt = (const float*)d_in[12];
  const float* nW0 = (const float*)d_in[13];
  const float* nb0 = (const float*)d_in[14];
  const float* nW1 = (const float*)d_in[15];
  const float* nb1 = (const float*)d_in[16];
  const float* ng  = (const float*)d_in[17];
  const float* nbt = (const float*)d_in[18];
  const float* dW0 = (const float*)d_in[19];
  const float* db0 = (const float*)d_in[20];
  const float* dW1 = (const float*)d_in[21];
  const float* db1 = (const float*)d_in[22];
  const float* uW0 = (const float*)d_in[23];
  const float* ub0 = (const float*)d_in[24];
  const float* uW1 = (const float*)d_in[25];
  const float* ub1 = (const float*)d_in[26];
  const float* ug  = (const float*)d_in[27];
  const float* ubt = (const float*)d_in[28];
  const float* oW  = (const float*)d_in[29];
  const float* ob  = (const float*)d_in[30];

  char* w = (char*)d_ws;
  auto alloc = [&](size_t bytes) -> char* {
    char* p = w; w += (bytes + 255) & ~(size_t)255; return p;
  };
  u16*   ea_s   = (u16*)alloc((size_t)ECNT * HD * 2);
  u16*   xa     = (u16*)alloc((size_t)NC * HD * 2);
  u16*   xb     = (u16*)alloc((size_t)NF * HD * 2);
  u16*   P      = (u16*)alloc((size_t)NC * HD * 2);
  u16*   Q      = (u16*)alloc((size_t)NC * HD * 2);
  u16*   XU     = (u16*)alloc((size_t)NC * HD * 2);
  int*   deg    = (int*)alloc((size_t)NF * 4);
  int*   rowptr = (int*)alloc((size_t)(NF + 1) * 4);
  int*   cursor = (int*)alloc((size_t)NF * 4);
  int*   perm   = (int*)alloc((size_t)ECNT * 4);
  int*   esrc   = (int*)alloc((size_t)ECNT * 4);
  int*   edst   = (int*)alloc((size_t)ECNT * 4);
  int*   part   = (int*)alloc((size_t)SCB * 4);
  u16*   c_eW0  = (u16*)alloc((size_t)2 * 384 * HD * 2);
  u16*   c_eW1  = (u16*)alloc((size_t)2 * HD * HD * 2);
  u16*   c_nW0  = (u16*)alloc((size_t)2 * 256 * HD * 2);
  u16*   c_nW1  = (u16*)alloc((size_t)2 * HD * HD * 2);
  u16*   c_uW0  = (u16*)alloc((size_t)256 * HD * 2);
  u16*   c_uW1  = (u16*)alloc((size_t)HD * HD * 2);
  u16*   c_dW1  = (u16*)alloc((size_t)HD * HD * 2);

  prep_all_kernel<<<1152, 256, 0, stream>>>(eW0, eW1, nW0, nW1, uW0, uW1, dW1,
                                            c_eW0, c_eW1, c_nW0, c_nW1, c_uW0, c_uW1, c_dW1);
  f32_to_bf16_vec<<<(NC * HD / 8 + 255) / 256, 256, 0, stream>>>(x_in, xa, NC * HD / 8);

  hipMemsetAsync(deg, 0, (size_t)NF * 4, stream);
  deg_kernel<<<(ECNT + 255) / 256, 256, 0, stream>>>(ei, deg);
  scanA_kernel<<<NB_SCAN, SCB, 0, stream>>>(deg, part);
  scanB_kernel<<<1, SCB, 0, stream>>>(part);
  scanC_kernel<<<NB_SCAN, SCB, 0, stream>>>(deg, part, rowptr);
  hipMemcpyAsync(cursor, rowptr, (size_t)NF * 4, hipMemcpyDeviceToDevice, stream);
  build_perm_kernel<<<(ECNT + 255) / 256, 256, 0, stream>>>(ei, cursor, perm, esrc, edst);

  auto grd = [](int rows){ return (rows + 31) / 32; };
  const int KS = 16 * HD * 8;   // u16 offset of one 128-K slice in chunked layout

  auto eslice = [&](int i, int s){ return c_eW0 + (size_t)i * 384 * HD + (size_t)s * KS; };

  auto edgeP = [&](int i){
    edge_kernel<1><<<grd(ECNT), 256, 0, stream>>>(
      eslice(i, 2), c_eW1 + (size_t)i*HD*HD,
      eb0 + i*HD, eb1 + i*HD, eg + i*HD, ebt + i*HD,
      ea_s, P, Q, esrc, edst, ea_s, perm, ea_in);
  };
  auto edge = [&](int i){
    edge_kernel<0><<<grd(ECNT), 256, 0, stream>>>(
      eslice(i, 2), c_eW1 + (size_t)i*HD*HD,
      eb0 + i*HD, eb1 + i*HD, eg + i*HD, ebt + i*HD,
      ea_s, P, Q, esrc, edst, ea_s, nullptr, nullptr);
  };
  auto node = [&](u16* x, int n, int i, int F,
                  const u16* Wf0, const u16* Wf1, u16* oF0, u16* oF1){
    if (F == 2)
      mlp_kernel<M_NODE, 2><<<grd(n), 256, 0, stream>>>(
        c_nW0 + (size_t)i*256*HD, c_nW0 + (size_t)i*256*HD + KS, c_nW1 + (size_t)i*HD*HD,
        nb0 + i*HD, nb1 + i*HD, nullptr, ng + i*HD, nbt + i*HD,
        x, nullptr, rowptr, ea_s, nullptr,
        x, n, nullptr, nullptr, nullptr, nullptr, Wf0, Wf1, oF0, oF1, NC);
    else if (F == 1)
      mlp_kernel<M_NODE, 1><<<grd(n), 256, 0, stream>>>(
        c_nW0 + (size_t)i*256*HD, c_nW0 + (size_t)i*256*HD + KS, c_nW1 + (size_t)i*HD*HD,
        nb0 + i*HD, nb1 + i*HD, nullptr, ng + i*HD, nbt + i*HD,
        x, nullptr, rowptr, ea_s, nullptr,
        x, n, nullptr, nullptr, nullptr, nullptr, Wf0, nullptr, oF0, nullptr, NC);
    else
      mlp_kernel<M_NODE, 0><<<grd(n), 256, 0, stream>>>(
        c_nW0 + (size_t)i*256*HD, c_nW0 + (size_t)i*256*HD + KS, c_nW1 + (size_t)i*HD*HD,
        nb0 + i*HD, nb1 + i*HD, nullptr, ng + i*HD, nbt + i*HD,
        x, nullptr, rowptr, ea_s, nullptr,
        x, n, nullptr, nullptr, nullptr, nullptr, nullptr, nullptr, nullptr, nullptr, 0);
  };

  // ---- pass 1 on xa ----
  lin2_kernel<<<grd(NC), 256, 0, stream>>>(eslice(0,0), eslice(0,1), xa, P, Q, NC);
  edgeP(0);                                                    // gathers + converts ea inline
  node(xa, NC, 0, 2, eslice(1,0), eslice(1,1), P, Q);          // next-iter P,Q
  edge(1);
  node(xa, NC, 1, 1, c_uW0 + KS, nullptr, XU, nullptr);        // XU = xa @ uW0b

  // ---- decoder (fused DEC1+DEC2), fuses pass-2 first P,Q ----
  mlp_kernel<M_DEC12, 2><<<grd(NF), 256, 0, stream>>>(
    c_dW1, c_uW0, c_uW1,
    db1, ub0, ub1, ug, ubt,
    nullptr, XU, nullptr, nullptr, clus,
    xb, NF, dW0, db0, pos_c, pos_f,
    eslice(0,0), eslice(0,1), P, Q, NC);

  // ---- pass 2 on xb ----
  edge(0);
  node(xb, NF, 0, 2, eslice(1,0), eslice(1,1), P, Q);
  edge(1);
  node(xb, NF, 1, 0, nullptr, nullptr, nullptr, nullptr);

  float* out = (float*)d_out;
  outhead_kernel<<<(NF + 3) / 4, 256, 0, stream>>>(xb, oW, ob, out);
  idxcopy_kernel<<<(2 * ECNT + 255) / 256, 256, 0, stream>>>(ei, out + (size_t)NF * OUTD);
}